// Round 5
// baseline (1933.247 us; speedup 1.0000x reference)
//
#include <hip/hip_runtime.h>
#include <hip/hip_bf16.h>
#include <math.h>

typedef __hip_bfloat16 bf16;
typedef __attribute__((ext_vector_type(8))) short short8;   // 8 bf16 = 4 VGPRs
typedef __attribute__((ext_vector_type(4))) float f32x4;

#define Bb 4
#define Tt 2048
#define Cc 2048
#define Hh 32
#define Nn 64
#define BT (Bb*Tt)   // 8192
#define Gg 16        // scan chunks per (b,h)
#define Ll 128       // timesteps per chunk (Gg*Ll == Tt)
#define SPLITK 8     // K-split for skinny MFMA gemms

__device__ __forceinline__ float b2f(bf16 x) { return __bfloat162float(x); }
__device__ __forceinline__ bf16  f2b(float x) { return __float2bfloat16(x); }

// async global->LDS DMA, 16B per lane (wave-uniform LDS base + lane*16)
__device__ __forceinline__ void gload16(const bf16* g, bf16* l) {
  __builtin_amdgcn_global_load_lds(
      (const __attribute__((address_space(1))) void*)g,
      (__attribute__((address_space(3))) void*)l, 16, 0, 0);
}

// ---------------------------------------------------------------------------
// K0: fp32 -> bf16 weight conversion (for MFMA GEMMs)
// ---------------------------------------------------------------------------
__global__ __launch_bounds__(256) void cvt_kernel(
    const float* __restrict__ in, bf16* __restrict__ out)
{
  int i = blockIdx.x * 256 + threadIdx.x;
  out[i] = f2b(in[i]);
}

// ---------------------------------------------------------------------------
// K0b: fp32 [K,N] -> bf16 hi/lo [N,K] transpose-convert (K == 2048 fixed).
// hi = bf16(w); lo = bf16(w - hi). Two-MFMA accumulation recovers ~fp32 B.
// ---------------------------------------------------------------------------
__global__ __launch_bounds__(256) void cvt_t2_kernel(
    const float* __restrict__ in, bf16* __restrict__ hi, bf16* __restrict__ lo,
    int N)
{
  int idx = blockIdx.x * 256 + threadIdx.x;   // over N*2048
  int n = idx >> 11, k = idx & 2047;
  float v = in[(size_t)k * N + n];
  bf16 h = f2b(v);
  hi[idx] = h;
  lo[idx] = f2b(v - b2f(h));
}

// ---------------------------------------------------------------------------
// K0c: w2 fp32 [160, C] -> bf16 hi/lo [C, 160] transpose-convert.
// ---------------------------------------------------------------------------
__global__ __launch_bounds__(256) void cvt_w2t_kernel(
    const float* __restrict__ in, bf16* __restrict__ hi, bf16* __restrict__ lo)
{
  int idx = blockIdx.x * 256 + threadIdx.x;   // over 2048*160
  int c = idx / 160, e = idx - c * 160;
  float v = in[(size_t)e * Cc + c];
  bf16 h = f2b(v);
  hi[idx] = h;
  lo[idx] = f2b(v - b2f(h));
}

// ---------------------------------------------------------------------------
// K1: xm = x + (shift(x) - x) * time_maa_x
// ---------------------------------------------------------------------------
__global__ __launch_bounds__(256) void prep_xm_kernel(
    const float* __restrict__ x, const float* __restrict__ maa_x,
    bf16* __restrict__ xm)
{
  int idx = blockIdx.x * 256 + threadIdx.x;
  int c  = idx & (Cc - 1);
  int bt = idx >> 11;
  int t  = bt & (Tt - 1);
  float xv   = x[idx];
  float prev = (t == 0) ? 0.f : x[idx - Cc];
  xm[idx] = f2b(xv + (prev - xv) * maa_x[c]);
}

// ---------------------------------------------------------------------------
// MFMA GEMM (m97 structure): C[8192,2048] = A * B^T, B[2048,2048] ([N,K]).
// 128x128 tile, BK=32, LINEAR LDS [128][32] staged via global_load_lds
// dwordx4 (wave-uniform LDS base + lane*16B). 4 waves 2x2, each 64x64 via
// 4x4 16x16x32 MFMAs. mode: 0 plain->bf16, 2 silu->bf16, 4 plain->fp32
// ---------------------------------------------------------------------------
__global__ __launch_bounds__(256) void mfma_gemm_kernel(
    const bf16* __restrict__ A, const bf16* __restrict__ B,
    bf16* __restrict__ outB, float* __restrict__ outF, int mode)
{
  __shared__ bf16 As[128 * 32];
  __shared__ bf16 Bs[128 * 32];
  int tid  = threadIdx.x;
  int lane = tid & 63, wid = tid >> 6;
  int wm = wid & 1, wn = wid >> 1;
  int quad = lane >> 4, l16 = lane & 15;
  size_t rowBase = (size_t)blockIdx.x * 128;
  size_t colBase = (size_t)blockIdx.y * 128;

  // staging: 16KB/iter = 16 wave-segments of 1KB; wave w does A-seg {2w,2w+1}
  // and B-seg {2w,2w+1}. lane i covers row seg*16+(i>>2), col (i&3)*8.
  int seg0 = wid * 2, seg1 = seg0 + 1;
  int scol = (lane & 3) * 8;
  const bf16* ga0 = A + (rowBase + seg0 * 16 + (lane >> 2)) * 2048 + scol;
  const bf16* ga1 = A + (rowBase + seg1 * 16 + (lane >> 2)) * 2048 + scol;
  const bf16* gb0 = B + (colBase + seg0 * 16 + (lane >> 2)) * 2048 + scol;
  const bf16* gb1 = B + (colBase + seg1 * 16 + (lane >> 2)) * 2048 + scol;

  f32x4 acc[4][4];
  #pragma unroll
  for (int i = 0; i < 4; ++i)
    #pragma unroll
    for (int j = 0; j < 4; ++j)
      acc[i][j] = (f32x4){0.f, 0.f, 0.f, 0.f};

  for (int k0 = 0; k0 < 2048; k0 += 32) {
    gload16(ga0 + k0, As + seg0 * 512);
    gload16(ga1 + k0, As + seg1 * 512);
    gload16(gb0 + k0, Bs + seg0 * 512);
    gload16(gb1 + k0, Bs + seg1 * 512);
    __syncthreads();            // compiler drains vmcnt(0) before s_barrier
    short8 af[4], bf[4];
    #pragma unroll
    for (int i = 0; i < 4; ++i) {
      af[i] = *(const short8*)(As + (wm * 64 + i * 16 + l16) * 32 + quad * 8);
      bf[i] = *(const short8*)(Bs + (wn * 64 + i * 16 + l16) * 32 + quad * 8);
    }
    #pragma unroll
    for (int i = 0; i < 4; ++i)
      #pragma unroll
      for (int j = 0; j < 4; ++j)
        acc[i][j] = __builtin_amdgcn_mfma_f32_16x16x32_bf16(af[i], bf[j], acc[i][j], 0, 0, 0);
    __syncthreads();
  }

  #pragma unroll
  for (int i = 0; i < 4; ++i) {
    #pragma unroll
    for (int j = 0; j < 4; ++j) {
      int gc = colBase + wn * 64 + j * 16 + l16;
      #pragma unroll
      for (int reg = 0; reg < 4; ++reg) {
        int gr = rowBase + wm * 64 + i * 16 + quad * 4 + reg;
        float v = acc[i][j][reg];
        size_t idx = (size_t)gr * 2048 + gc;
        if (mode == 0)      outB[idx] = f2b(v);
        else if (mode == 2) outB[idx] = f2b(v / (1.f + expf(-v)));
        else                outF[idx] = v;
      }
    }
  }
}

// ---------------------------------------------------------------------------
// Skinny MFMA GEMM with split-K and hi/lo B compensation:
// C_partial[kseg][8192][N] = A_seg @ (Bhi+Blo)_seg^T.
// ---------------------------------------------------------------------------
#define LDA 40   // padded LDS row for VALU-staged tiles

template<int NF>
__global__ __launch_bounds__(256) void mfma_skinny_kernel(
    const bf16* __restrict__ A, const bf16* __restrict__ Bt_hi,
    const bf16* __restrict__ Bt_lo,
    float* __restrict__ partial, int kseg_len)
{
  constexpr int N = NF * 16;
  __shared__ bf16 As[64 * LDA];
  __shared__ bf16 Bs[2 * N * LDA];   // rows 0..N-1 hi, N..2N-1 lo
  int tid = threadIdx.x;
  int lane = tid & 63, w = tid >> 6;
  int quad = lane >> 4, l16 = lane & 15;
  int rowBase = blockIdx.x * 64;
  int kbeg = blockIdx.y * kseg_len;

  f32x4 acc[NF];
  #pragma unroll
  for (int f = 0; f < NF; ++f) acc[f] = (f32x4){0.f, 0.f, 0.f, 0.f};

  for (int k0 = kbeg; k0 < kbeg + kseg_len; k0 += 32) {
    // stage A 64x32 (256 threads x 8 elems)
    {
      int row = tid >> 2, kc = (tid & 3) * 8;
      *(short8*)(As + row * LDA + kc) =
          *(const short8*)(A + (size_t)(rowBase + row) * 2048 + k0 + kc);
    }
    // stage B hi and lo, N x 32 each
    for (int c = tid; c < N * 8; c += 256) {
      int half = c >= N * 4;
      int cc = c - half * N * 4;
      int row = cc >> 2, kc = (cc & 3) * 8;
      const bf16* src = half ? Bt_lo : Bt_hi;
      *(short8*)(Bs + (half * N + row) * LDA + kc) =
          *(const short8*)(src + (size_t)row * 2048 + k0 + kc);
    }
    __syncthreads();
    short8 af = *(const short8*)(As + (w * 16 + l16) * LDA + quad * 8);
    #pragma unroll
    for (int f = 0; f < NF; ++f) {
      short8 bh = *(const short8*)(Bs + (f * 16 + l16) * LDA + quad * 8);
      short8 bl = *(const short8*)(Bs + ((N + f * 16 + l16)) * LDA + quad * 8);
      acc[f] = __builtin_amdgcn_mfma_f32_16x16x32_bf16(af, bh, acc[f], 0, 0, 0);
      acc[f] = __builtin_amdgcn_mfma_f32_16x16x32_bf16(af, bl, acc[f], 0, 0, 0);
    }
    __syncthreads();
  }

  #pragma unroll
  for (int f = 0; f < NF; ++f) {
    int gc = f * 16 + l16;
    #pragma unroll
    for (int reg = 0; reg < 4; ++reg) {
      int gr = rowBase + w * 16 + quad * 4 + reg;
      partial[((size_t)blockIdx.y * 8192 + gr) * N + gc] = acc[f][reg];
    }
  }
}

// sum SPLITK partials + tanh -> bf16
__global__ __launch_bounds__(256) void reduce_tanh_kernel(
    const float* __restrict__ partial, bf16* __restrict__ out, int MN)
{
  int idx = blockIdx.x * 256 + threadIdx.x;
  float s = 0.f;
  #pragma unroll
  for (int j = 0; j < SPLITK; ++j) s += partial[(size_t)j * MN + idx];
  out[idx] = f2b(tanhf(s));
}

// ---------------------------------------------------------------------------
// VALU tiled GEMM (still used for td: M=8192,N=2048,K=64). A bf16, B fp32.
// mode: 1 tanh->bf16, 3 td = bias[n]+acc -> bf16
// ---------------------------------------------------------------------------
#define BM 128
#define BN 128
#define BKk 16

__global__ __launch_bounds__(256) void gemm_kernel(
    const bf16* __restrict__ A, const float* __restrict__ Bm,
    bf16* __restrict__ outB,
    const float* __restrict__ bias,
    int M, int N, int K, int transB, int mode)
{
  __shared__ float As[BKk][BM + 1];
  __shared__ float Bs[BKk][BN + 1];
  int tid = threadIdx.x;
  int rowBase = blockIdx.x * BM;
  int colBase = blockIdx.y * BN;
  int tx = tid & 15, ty = tid >> 4;
  float acc[8][8];
  #pragma unroll
  for (int i = 0; i < 8; ++i)
    #pragma unroll
    for (int j = 0; j < 8; ++j) acc[i][j] = 0.f;

  for (int k0 = 0; k0 < K; k0 += BKk) {
    #pragma unroll
    for (int i = 0; i < 8; ++i) {
      int lin = tid + i * 256;
      int r = lin >> 4, kk = lin & 15;
      int gr = rowBase + r, gk = k0 + kk;
      float val = 0.f;
      if (gr < M && gk < K) val = b2f(A[(size_t)gr * K + gk]);
      As[kk][r] = val;
    }
    #pragma unroll
    for (int i = 0; i < 8; ++i) {
      int lin = tid + i * 256;
      float val = 0.f;
      if (transB) {
        int n = lin >> 4, kk = lin & 15;
        int gn = colBase + n, gk = k0 + kk;
        if (gn < N && gk < K) val = Bm[(size_t)gn * K + gk];
        Bs[kk][n] = val;
      } else {
        int kk = lin >> 7, n = lin & 127;
        int gn = colBase + n, gk = k0 + kk;
        if (gn < N && gk < K) val = Bm[(size_t)gk * N + gn];
        Bs[kk][n] = val;
      }
    }
    __syncthreads();
    #pragma unroll
    for (int kk = 0; kk < BKk; ++kk) {
      float a[8], b[8];
      #pragma unroll
      for (int i = 0; i < 8; ++i) a[i] = As[kk][ty * 8 + i];
      #pragma unroll
      for (int j = 0; j < 8; ++j) b[j] = Bs[kk][tx * 8 + j];
      #pragma unroll
      for (int i = 0; i < 8; ++i)
        #pragma unroll
        for (int j = 0; j < 8; ++j)
          acc[i][j] = fmaf(a[i], b[j], acc[i][j]);
    }
    __syncthreads();
  }
  #pragma unroll
  for (int i = 0; i < 8; ++i) {
    int gr = rowBase + ty * 8 + i;
    if (gr >= M) continue;
    #pragma unroll
    for (int j = 0; j < 8; ++j) {
      int gn = colBase + tx * 8 + j;
      if (gn >= N) continue;
      float v = acc[i][j];
      size_t idx = (size_t)gr * N + gn;
      if (mode == 1)      outB[idx] = f2b(tanhf(v));
      else                outB[idx] = f2b(bias[gn] + v);   // mode 3
    }
  }
}

// ---------------------------------------------------------------------------
// K3: fused 5-way token-shift lerp via MFMA (K=32, fragments from global).
// ---------------------------------------------------------------------------
__global__ __launch_bounds__(256) void lerp5_mfma_kernel(
    const float* __restrict__ x, const bf16* __restrict__ t5,
    const bf16* __restrict__ w2t_hi, const bf16* __restrict__ w2t_lo,
    const float* __restrict__ maa_w, const float* __restrict__ maa_k,
    const float* __restrict__ maa_v, const float* __restrict__ maa_r,
    const float* __restrict__ maa_g,
    bf16* __restrict__ xd, bf16* __restrict__ xk, bf16* __restrict__ xv_,
    bf16* __restrict__ xr, bf16* __restrict__ xg)
{
  int tid  = threadIdx.x;
  int lane = tid & 63, wid = tid >> 6;
  int wm = wid & 1, wn = wid >> 1;
  int quad = lane >> 4, l16 = lane & 15;
  int rowBase = blockIdx.x * 128;
  int colBase = blockIdx.y * 128;

  const float* maas[5] = {maa_w, maa_k, maa_v, maa_r, maa_g};
  bf16* outs[5] = {xd, xk, xv_, xr, xg};

  #pragma unroll
  for (int f = 0; f < 5; ++f) {
    short8 af[4];
    #pragma unroll
    for (int i = 0; i < 4; ++i)
      af[i] = *(const short8*)(t5 +
          (size_t)(rowBase + wm * 64 + i * 16 + l16) * 160 + f * 32 + quad * 8);

    f32x4 acc[4][4];
    #pragma unroll
    for (int i = 0; i < 4; ++i)
      #pragma unroll
      for (int j = 0; j < 4; ++j)
        acc[i][j] = (f32x4){0.f, 0.f, 0.f, 0.f};

    #pragma unroll
    for (int j = 0; j < 4; ++j) {
      size_t boff = (size_t)(colBase + wn * 64 + j * 16 + l16) * 160 + f * 32 + quad * 8;
      short8 bh = *(const short8*)(w2t_hi + boff);
      short8 bl = *(const short8*)(w2t_lo + boff);
      #pragma unroll
      for (int i = 0; i < 4; ++i) {
        acc[i][j] = __builtin_amdgcn_mfma_f32_16x16x32_bf16(af[i], bh, acc[i][j], 0, 0, 0);
        acc[i][j] = __builtin_amdgcn_mfma_f32_16x16x32_bf16(af[i], bl, acc[i][j], 0, 0, 0);
      }
    }

    const float* maa = maas[f];
    bf16* outp = outs[f];
    #pragma unroll
    for (int j = 0; j < 4; ++j) {
      int gc = colBase + wn * 64 + j * 16 + l16;
      float mv = maa[gc];
      #pragma unroll
      for (int i = 0; i < 4; ++i) {
        #pragma unroll
        for (int reg = 0; reg < 4; ++reg) {
          int gr = rowBase + wm * 64 + i * 16 + quad * 4 + reg;
          size_t idx = (size_t)gr * Cc + gc;
          float xv0  = x[idx];
          float prev = ((gr & (Tt - 1)) == 0) ? 0.f : x[idx - Cc];
          outp[idx] = f2b(xv0 + (prev - xv0) * (mv + acc[i][j][reg]));
        }
      }
    }
  }
}

// ---------------------------------------------------------------------------
// K5a: chunked WKV local scan. Grid = B*H*G. 1 barrier/step (dbuf).
// ---------------------------------------------------------------------------
__global__ __launch_bounds__(256) void wkv_local_kernel(
    const bf16* __restrict__ k, const bf16* __restrict__ v,
    const bf16* __restrict__ td,
    float* __restrict__ S_local, float* __restrict__ wp)
{
  int bh = blockIdx.x >> 4;          // Gg == 16
  int c  = blockIdx.x & 15;
  int b  = bh >> 5, h = bh & 31;
  int tid = threadIdx.x;
  int m = tid & 63, chunk = tid >> 6;
  __shared__ float kw[2][64][2];     // [buf][ch][{k,w}]
  __shared__ float vsb[2][64];
  float s[16], wpr[16];
  #pragma unroll
  for (int i = 0; i < 16; ++i) { s[i] = 0.f; wpr[i] = 1.f; }
  size_t base = (size_t)b * Tt * Cc + (size_t)(c * Ll) * Cc + (size_t)h * 64;
  for (int t = 0; t < Ll; ++t, base += Cc) {
    int p = t & 1;
    int role = tid >> 6, ch = tid & 63;
    if (role == 0)      kw[p][ch][0] = b2f(k[base + ch]);
    else if (role == 1) kw[p][ch][1] = expf(-expf(b2f(td[base + ch])));
    else if (role == 2) vsb[p][ch]   = b2f(v[base + ch]);
    __syncthreads();
    float vm = vsb[p][m];
    #pragma unroll
    for (int i = 0; i < 16; ++i) {
      float kk = kw[p][chunk * 16 + i][0];
      float ww = kw[p][chunk * 16 + i][1];
      s[i] = fmaf(ww, s[i], kk * vm);
      wpr[i] *= ww;
    }
  }
  size_t sb = ((size_t)blockIdx.x * 64 + chunk * 16) * 64 + m;
  #pragma unroll
  for (int i = 0; i < 16; ++i) S_local[sb + (size_t)i * 64] = s[i];
  if (m == 0) {
    int wb = blockIdx.x * 64 + chunk * 16;
    #pragma unroll
    for (int i = 0; i < 16; ++i) wp[wb + i] = wpr[i];
  }
}

// ---------------------------------------------------------------------------
// K5b: chunk-prefix combine over Gg=16 chunks, parallel over (b,h,n,m).
// ---------------------------------------------------------------------------
__global__ __launch_bounds__(256) void wkv_combine_kernel(
    const float* __restrict__ S_local, const float* __restrict__ wp,
    float* __restrict__ S_start)
{
  int idx = blockIdx.x * 256 + threadIdx.x;   // over B*H*N*N
  int m = idx & 63;
  int n = (idx >> 6) & 63;
  int bh = idx >> 12;
  float cur = 0.f;
  #pragma unroll
  for (int c = 0; c < Gg; ++c) {
    size_t sbase = (((size_t)(bh * Gg + c)) * 64 + n) * 64 + m;
    S_start[sbase] = cur;
    cur = fmaf(wp[(bh * Gg + c) * 64 + n], cur, S_local[sbase]);
  }
}

// ---------------------------------------------------------------------------
// K5c: chunked WKV output scan, seeded from S_start; writes in place over td.
// Now 1 barrier/step: double-buffered staging + red, output deferred 1 step.
// ---------------------------------------------------------------------------
__global__ __launch_bounds__(256) void wkv_out_kernel(
    const bf16* __restrict__ r, const bf16* __restrict__ k,
    const bf16* __restrict__ v, const bf16* __restrict__ td,
    const float* __restrict__ u, const float* __restrict__ S_start,
    bf16* __restrict__ out)
{
  int bh = blockIdx.x >> 4;
  int c  = blockIdx.x & 15;
  int b  = bh >> 5, h = bh & 31;
  int tid = threadIdx.x;
  int m = tid & 63, chunk = tid >> 6;
  __shared__ float4 rkw[2][64];
  __shared__ float vsb[2][64];
  __shared__ float red[2][256];
  float s[16], ureg[16];
  size_t sb = ((size_t)blockIdx.x * 64 + chunk * 16) * 64 + m;
  #pragma unroll
  for (int i = 0; i < 16; ++i) {
    s[i]    = S_start[sb + (size_t)i * 64];
    ureg[i] = u[h * 64 + chunk * 16 + i];
  }
  size_t base = (size_t)b * Tt * Cc + (size_t)(c * Ll) * Cc + (size_t)h * 64;
  for (int t = 0; t < Ll; ++t, base += Cc) {
    int p = t & 1;
    int role = tid >> 6, ch = tid & 63;
    if (role == 0)      rkw[p][ch].x = b2f(r[base + ch]);
    else if (role == 1) rkw[p][ch].y = b2f(k[base + ch]);
    else if (role == 2) rkw[p][ch].z = expf(-expf(b2f(td[base + ch])));
    else                vsb[p][ch]   = b2f(v[base + ch]);
    __syncthreads();
    // after barrier: buf[p] staged AND red[p^1] (step t-1) complete
    if (t > 0 && tid < 64) {
      int q = p ^ 1;
      out[base - Cc + tid] =
          f2b(red[q][tid] + red[q][tid + 64] + red[q][tid + 128] + red[q][tid + 192]);
    }
    float vm = vsb[p][m];
    float acc = 0.f;
    #pragma unroll
    for (int i = 0; i < 16; ++i) {
      float4 q4 = rkw[p][chunk * 16 + i];
      float kv = q4.y * vm;
      acc = fmaf(q4.x, fmaf(ureg[i], kv, s[i]), acc);
      s[i] = fmaf(q4.z, s[i], kv);
    }
    red[p][tid] = acc;
  }
  __syncthreads();
  int q = (Ll - 1) & 1;
  if (tid < 64)
    out[base - Cc + tid] =
        f2b(red[q][tid] + red[q][tid + 64] + red[q][tid + 128] + red[q][tid + 192]);
}

// ---------------------------------------------------------------------------
// K6: GroupNorm over each head (N=64) + affine + gate with g
// ---------------------------------------------------------------------------
__global__ __launch_bounds__(256) void gn_gate_kernel(
    const bf16* __restrict__ wkv, const bf16* __restrict__ g,
    const float* __restrict__ lnw, const float* __restrict__ lnb,
    bf16* __restrict__ out)
{
  int bt = blockIdx.x;
  int wv = threadIdx.x >> 6, lane = threadIdx.x & 63;
  const float EPS = 6.4e-4f;   // 1e-5 * 8^2
  for (int h = wv; h < Hh; h += 4) {
    size_t base = (size_t)bt * Cc + h * 64;
    float x = b2f(wkv[base + lane]);
    float s = x, s2 = x * x;
    #pragma unroll
    for (int off = 1; off < 64; off <<= 1) {
      s  += __shfl_xor(s, off);
      s2 += __shfl_xor(s2, off);
    }
    float mean = s * (1.f / 64.f);
    float var  = s2 * (1.f / 64.f) - mean * mean;
    float inv  = rsqrtf(var + EPS);
    float normed = (x - mean) * inv * lnw[h * 64 + lane] + lnb[h * 64 + lane];
    out[base + lane] = f2b(normed * b2f(g[base + lane]));
  }
}

// ---------------------------------------------------------------------------
// Workspace map: 5 x 33.55 MB bf16 [BT,C] + 8 MB small-region + 5 x 8.39 MB
// bf16 weights ~= 218 MB. Small-region layout (offsets from ws+5*BUF):
//   +0      t5buf (2.5 MB bf16), doubles as wp (512 KB fp32) at scan time
//   +4 MB   abuf (1 MB bf16)
//   +5 MB   w1t_hi (640 KB), +5.75 MB w1t_lo (640 KB)
//   +6.5 MB dw1t_hi (256 KB), +6.75 MB dw1t_lo (256 KB)
// d_out (67 MB): bytes 0..42 MB = skinny-gemm fp32 partials (stages 2,4);
// bytes 48..49.3 MB = w2t hi/lo (consumed at stage 3); then lower half =
// bf16 r-scratch + upper half = S_local (stage 5+). S_start reuses buf0.
// ---------------------------------------------------------------------------
extern "C" void kernel_launch(void* const* d_in, const int* in_sizes, int n_in,
                              void* d_out, int out_size, void* d_ws, size_t ws_size,
                              hipStream_t stream) {
  const float* hidden = (const float*)d_in[0];
  const float* maa_x  = (const float*)d_in[1];
  const float* maa_w  = (const float*)d_in[2];
  const float* maa_k  = (const float*)d_in[3];
  const float* maa_v  = (const float*)d_in[4];
  const float* maa_r  = (const float*)d_in[5];
  const float* maa_g  = (const float*)d_in[6];
  const float* maa_w1 = (const float*)d_in[7];   // [C,160]
  const float* maa_w2 = (const float*)d_in[8];   // [160,C]
  const float* tdecay = (const float*)d_in[9];   // [C]
  const float* dw1    = (const float*)d_in[10];  // [C,64]
  const float* dw2    = (const float*)d_in[11];  // [64,C]
  const float* faaaa  = (const float*)d_in[12];  // [H,N]
  const float* w_r    = (const float*)d_in[13];
  const float* w_k    = (const float*)d_in[14];
  const float* w_v    = (const float*)d_in[15];
  const float* w_g    = (const float*)d_in[16];
  const float* w_o    = (const float*)d_in[17];
  const float* lnw    = (const float*)d_in[18];
  const float* lnb    = (const float*)d_in[19];
  float* outF = (float*)d_out;
  bf16* rscratch = (bf16*)d_out;

  char* ws = (char*)d_ws;
  const size_t BUF  = (size_t)BT * Cc * sizeof(bf16);   // 33,554,432 B
  const size_t WBUF = (size_t)Cc * Cc * sizeof(bf16);   //  8,388,608 B
  const size_t MB = 1024 * 1024;
  bf16* buf0 = (bf16*)(ws + 0 * BUF);
  bf16* buf1 = (bf16*)(ws + 1 * BUF);
  bf16* buf2 = (bf16*)(ws + 2 * BUF);
  bf16* buf3 = (bf16*)(ws + 3 * BUF);
  bf16* buf4 = (bf16*)(ws + 4 * BUF);
  char* small = ws + 5 * BUF;
  bf16* t5buf   = (bf16*)(small + 0);
  bf16* abuf    = (bf16*)(small + 4 * MB);
  bf16* w1t_hi  = (bf16*)(small + 5 * MB);
  bf16* w1t_lo  = (bf16*)(small + 5 * MB + 768 * 1024);
  bf16* dw1t_hi = (bf16*)(small + 6 * MB + 512 * 1024);
  bf16* dw1t_lo = (bf16*)(small + 6 * MB + 768 * 1024);
  char* wbase = small + 8 * MB;
  bf16* wrb = (bf16*)(wbase + 0 * WBUF);
  bf16* wkb = (bf16*)(wbase + 1 * WBUF);
  bf16* wvb = (bf16*)(wbase + 2 * WBUF);
  bf16* wgb = (bf16*)(wbase + 3 * WBUF);
  bf16* wob = (bf16*)(wbase + 4 * WBUF);

  // w2t hi/lo (640 KB each) live in d_out above the skinny partials
  bf16* w2t_hi = (bf16*)((char*)d_out + 48 * MB);
  bf16* w2t_lo = (bf16*)((char*)d_out + 49 * MB);

  // scan scratch: S_local in d_out upper half, S_start in buf0, wp in t5buf
  float* slbuf = (float*)((char*)d_out + BUF);   // 33.55 MB fp32
  float* ssbuf = (float*)buf0;                   // 33.55 MB fp32
  float* wpbuf = (float*)t5buf;                  // 512 KB fp32
  // skinny-gemm partial scratch: d_out bytes 0..42 MB (free until stage 5)
  float* pbuf  = (float*)d_out;

  dim3 blk(256);
  const int CVT_G = Cc * Cc / 256;   // 16384

  // 0. weight conversions (independent of data pipeline)
  cvt_kernel<<<dim3(CVT_G), blk, 0, stream>>>(w_r, wrb);
  cvt_kernel<<<dim3(CVT_G), blk, 0, stream>>>(w_k, wkb);
  cvt_kernel<<<dim3(CVT_G), blk, 0, stream>>>(w_v, wvb);
  cvt_kernel<<<dim3(CVT_G), blk, 0, stream>>>(w_g, wgb);
  cvt_kernel<<<dim3(CVT_G), blk, 0, stream>>>(w_o, wob);
  cvt_t2_kernel<<<dim3(160 * Cc / 256), blk, 0, stream>>>(maa_w1, w1t_hi, w1t_lo, 160);
  cvt_t2_kernel<<<dim3(64 * Cc / 256), blk, 0, stream>>>(dw1, dw1t_hi, dw1t_lo, 64);
  cvt_w2t_kernel<<<dim3(160 * Cc / 256), blk, 0, stream>>>(maa_w2, w2t_hi, w2t_lo);

  // 1. xm -> buf0
  prep_xm_kernel<<<dim3(BT * Cc / 256), blk, 0, stream>>>(hidden, maa_x, buf0);

  // 2. t5 = tanh(xm @ maa_w1): M=8192,N=160,K=2048 via split-K MFMA (hi/lo)
  mfma_skinny_kernel<10><<<dim3(128, SPLITK), blk, 0, stream>>>(
      buf0, w1t_hi, w1t_lo, pbuf, 2048 / SPLITK);
  reduce_tanh_kernel<<<dim3(BT * 160 / 256), blk, 0, stream>>>(pbuf, t5buf,
                                                               BT * 160);

  // 3. fused lerp (MFMA) -> xd(1) xk(2) xv(3) xr(4) xg(0)
  lerp5_mfma_kernel<<<dim3(64, 16), blk, 0, stream>>>(hidden, t5buf,
      w2t_hi, w2t_lo, maa_w, maa_k, maa_v, maa_r, maa_g,
      buf1, buf2, buf3, buf4, buf0);

  // 4. decay: a = tanh(xd @ dw1) [8192,64] via split-K MFMA (hi/lo);
  //    td = tdecay + a @ dw2 -> buf1 (VALU gemm, K=64)
  mfma_skinny_kernel<4><<<dim3(128, SPLITK), blk, 0, stream>>>(
      buf1, dw1t_hi, dw1t_lo, pbuf, 2048 / SPLITK);
  reduce_tanh_kernel<<<dim3(BT * 64 / 256), blk, 0, stream>>>(pbuf, abuf,
                                                              BT * 64);
  gemm_kernel<<<dim3(64, 16), blk, 0, stream>>>(abuf, dw2, buf1, tdecay,
                                                BT, Cc, 64, 0, 3);

  // 5. projections (MFMA): r->rscratch, k->buf4, v->buf2, g(silu)->buf3
  mfma_gemm_kernel<<<dim3(64, 16), blk, 0, stream>>>(buf4, wrb, rscratch, nullptr, 0);
  mfma_gemm_kernel<<<dim3(64, 16), blk, 0, stream>>>(buf2, wkb, buf4, nullptr, 0);
  mfma_gemm_kernel<<<dim3(64, 16), blk, 0, stream>>>(buf3, wvb, buf2, nullptr, 0);
  mfma_gemm_kernel<<<dim3(64, 16), blk, 0, stream>>>(buf0, wgb, buf3, nullptr, 2);

  // 6. chunked WKV scan: r=rscratch, k=buf4, v=buf2, td=buf1 -> out over buf1
  wkv_local_kernel<<<dim3(Bb * Hh * Gg), blk, 0, stream>>>(buf4, buf2, buf1,
                                                           slbuf, wpbuf);
  wkv_combine_kernel<<<dim3(Bb * Hh * Nn * Nn / 256), blk, 0, stream>>>(
      slbuf, wpbuf, ssbuf);
  wkv_out_kernel<<<dim3(Bb * Hh * Gg), blk, 0, stream>>>(rscratch, buf4, buf2,
      buf1, faaaa, ssbuf, buf1);

  // 7. GroupNorm + gate -> buf4 (wkv out now lives in buf1)
  gn_gate_kernel<<<dim3(BT), blk, 0, stream>>>(buf1, buf3, lnw, lnb, buf4);

  // 8. final projection (MFMA) -> d_out fp32
  mfma_gemm_kernel<<<dim3(64, 16), blk, 0, stream>>>(buf4, wob, nullptr, outF, 4);
}

// Round 6
// 1765.028 us; speedup vs baseline: 1.0953x; 1.0953x over previous
//
#include <hip/hip_runtime.h>
#include <hip/hip_bf16.h>
#include <math.h>

typedef __hip_bfloat16 bf16;
typedef __attribute__((ext_vector_type(8))) short short8;   // 8 bf16 = 4 VGPRs
typedef __attribute__((ext_vector_type(4))) float f32x4;

#define Bb 4
#define Tt 2048
#define Cc 2048
#define Hh 32
#define Nn 64
#define BT (Bb*Tt)   // 8192
#define Gg 16        // scan chunks per (b,h)
#define Ll 128       // timesteps per chunk (Gg*Ll == Tt)
#define SPLITK 8     // K-split for skinny MFMA gemms

__device__ __forceinline__ float b2f(bf16 x) { return __bfloat162float(x); }
__device__ __forceinline__ bf16  f2b(float x) { return __float2bfloat16(x); }

// ---------------------------------------------------------------------------
// K0: fp32 -> bf16 weight conversion (for MFMA GEMMs)
// ---------------------------------------------------------------------------
__global__ __launch_bounds__(256) void cvt_kernel(
    const float* __restrict__ in, bf16* __restrict__ out)
{
  int i = blockIdx.x * 256 + threadIdx.x;
  out[i] = f2b(in[i]);
}

// ---------------------------------------------------------------------------
// K0b: fp32 [K,N] -> bf16 hi/lo [N,K] transpose-convert (K == 2048 fixed).
// hi = bf16(w); lo = bf16(w - hi). Two-MFMA accumulation recovers ~fp32 B.
// ---------------------------------------------------------------------------
__global__ __launch_bounds__(256) void cvt_t2_kernel(
    const float* __restrict__ in, bf16* __restrict__ hi, bf16* __restrict__ lo,
    int N)
{
  int idx = blockIdx.x * 256 + threadIdx.x;   // over N*2048
  int n = idx >> 11, k = idx & 2047;
  float v = in[(size_t)k * N + n];
  bf16 h = f2b(v);
  hi[idx] = h;
  lo[idx] = f2b(v - b2f(h));
}

// ---------------------------------------------------------------------------
// K0c: w2 fp32 [160, C] -> bf16 hi/lo [C, 160] transpose-convert.
// ---------------------------------------------------------------------------
__global__ __launch_bounds__(256) void cvt_w2t_kernel(
    const float* __restrict__ in, bf16* __restrict__ hi, bf16* __restrict__ lo)
{
  int idx = blockIdx.x * 256 + threadIdx.x;   // over 2048*160
  int c = idx / 160, e = idx - c * 160;
  float v = in[(size_t)e * Cc + c];
  bf16 h = f2b(v);
  hi[idx] = h;
  lo[idx] = f2b(v - b2f(h));
}

// ---------------------------------------------------------------------------
// K1: xm = x + (shift(x) - x) * time_maa_x
// ---------------------------------------------------------------------------
__global__ __launch_bounds__(256) void prep_xm_kernel(
    const float* __restrict__ x, const float* __restrict__ maa_x,
    bf16* __restrict__ xm)
{
  int idx = blockIdx.x * 256 + threadIdx.x;
  int c  = idx & (Cc - 1);
  int bt = idx >> 11;
  int t  = bt & (Tt - 1);
  float xv   = x[idx];
  float prev = (t == 0) ? 0.f : x[idx - Cc];
  xm[idx] = f2b(xv + (prev - xv) * maa_x[c]);
}

// ---------------------------------------------------------------------------
// MFMA GEMM (R4 version — LDA=40 padded VALU staging; the global_load_lds
// variant regressed: linear 64B rows -> 8-way ds_read_b128 bank conflicts).
// C[8192,2048] = A * B^T. 128x128 tile, 4 waves 2x2, 4x4 16x16x32 MFMAs.
// mode: 0 plain->bf16, 2 silu->bf16, 4 plain->fp32
// ---------------------------------------------------------------------------
#define LDA 40   // padded LDS row (bf16 elems): 20 dwords -> ~2-way conflicts

__global__ __launch_bounds__(256) void mfma_gemm_kernel(
    const bf16* __restrict__ A, const bf16* __restrict__ B,
    bf16* __restrict__ outB, float* __restrict__ outF, int mode)
{
  __shared__ bf16 As[128 * LDA];
  __shared__ bf16 Bs[128 * LDA];
  int tid  = threadIdx.x;
  int lane = tid & 63, wid = tid >> 6;
  int wm = wid & 1, wn = wid >> 1;
  int quad = lane >> 4, l16 = lane & 15;
  size_t rowBase = (size_t)blockIdx.x * 128;
  size_t colBase = (size_t)blockIdx.y * 128;

  f32x4 acc[4][4];
  #pragma unroll
  for (int i = 0; i < 4; ++i)
    #pragma unroll
    for (int j = 0; j < 4; ++j)
      acc[i][j] = (f32x4){0.f, 0.f, 0.f, 0.f};

  for (int k0 = 0; k0 < 2048; k0 += 32) {
    #pragma unroll
    for (int pass = 0; pass < 2; ++pass) {
      int chunk = tid + pass * 256;           // 0..511
      int row = chunk >> 2, kc = (chunk & 3) * 8;
      short8 av = *(const short8*)(A + (rowBase + row) * 2048 + k0 + kc);
      short8 bv = *(const short8*)(B + (colBase + row) * 2048 + k0 + kc);
      *(short8*)(As + row * LDA + kc) = av;
      *(short8*)(Bs + row * LDA + kc) = bv;
    }
    __syncthreads();
    short8 af[4], bf[4];
    #pragma unroll
    for (int i = 0; i < 4; ++i) {
      af[i] = *(const short8*)(As + (wm * 64 + i * 16 + l16) * LDA + quad * 8);
      bf[i] = *(const short8*)(Bs + (wn * 64 + i * 16 + l16) * LDA + quad * 8);
    }
    #pragma unroll
    for (int i = 0; i < 4; ++i)
      #pragma unroll
      for (int j = 0; j < 4; ++j)
        acc[i][j] = __builtin_amdgcn_mfma_f32_16x16x32_bf16(af[i], bf[j], acc[i][j], 0, 0, 0);
    __syncthreads();
  }

  #pragma unroll
  for (int i = 0; i < 4; ++i) {
    #pragma unroll
    for (int j = 0; j < 4; ++j) {
      int gc = colBase + wn * 64 + j * 16 + l16;
      #pragma unroll
      for (int reg = 0; reg < 4; ++reg) {
        int gr = rowBase + wm * 64 + i * 16 + quad * 4 + reg;
        float v = acc[i][j][reg];
        size_t idx = (size_t)gr * 2048 + gc;
        if (mode == 0)      outB[idx] = f2b(v);
        else if (mode == 2) outB[idx] = f2b(v / (1.f + expf(-v)));
        else                outF[idx] = v;
      }
    }
  }
}

// ---------------------------------------------------------------------------
// Skinny MFMA GEMM with split-K and hi/lo B compensation:
// C_partial[kseg][8192][N] = A_seg @ (Bhi+Blo)_seg^T.
// ---------------------------------------------------------------------------
template<int NF>
__global__ __launch_bounds__(256) void mfma_skinny_kernel(
    const bf16* __restrict__ A, const bf16* __restrict__ Bt_hi,
    const bf16* __restrict__ Bt_lo,
    float* __restrict__ partial, int kseg_len)
{
  constexpr int N = NF * 16;
  __shared__ bf16 As[64 * LDA];
  __shared__ bf16 Bs[2 * N * LDA];   // rows 0..N-1 hi, N..2N-1 lo
  int tid = threadIdx.x;
  int lane = tid & 63, w = tid >> 6;
  int quad = lane >> 4, l16 = lane & 15;
  int rowBase = blockIdx.x * 64;
  int kbeg = blockIdx.y * kseg_len;

  f32x4 acc[NF];
  #pragma unroll
  for (int f = 0; f < NF; ++f) acc[f] = (f32x4){0.f, 0.f, 0.f, 0.f};

  for (int k0 = kbeg; k0 < kbeg + kseg_len; k0 += 32) {
    {
      int row = tid >> 2, kc = (tid & 3) * 8;
      *(short8*)(As + row * LDA + kc) =
          *(const short8*)(A + (size_t)(rowBase + row) * 2048 + k0 + kc);
    }
    for (int c = tid; c < N * 8; c += 256) {
      int half = c >= N * 4;
      int cc = c - half * N * 4;
      int row = cc >> 2, kc = (cc & 3) * 8;
      const bf16* src = half ? Bt_lo : Bt_hi;
      *(short8*)(Bs + (half * N + row) * LDA + kc) =
          *(const short8*)(src + (size_t)row * 2048 + k0 + kc);
    }
    __syncthreads();
    short8 af = *(const short8*)(As + (w * 16 + l16) * LDA + quad * 8);
    #pragma unroll
    for (int f = 0; f < NF; ++f) {
      short8 bh = *(const short8*)(Bs + (f * 16 + l16) * LDA + quad * 8);
      short8 bl = *(const short8*)(Bs + ((N + f * 16 + l16)) * LDA + quad * 8);
      acc[f] = __builtin_amdgcn_mfma_f32_16x16x32_bf16(af, bh, acc[f], 0, 0, 0);
      acc[f] = __builtin_amdgcn_mfma_f32_16x16x32_bf16(af, bl, acc[f], 0, 0, 0);
    }
    __syncthreads();
  }

  #pragma unroll
  for (int f = 0; f < NF; ++f) {
    int gc = f * 16 + l16;
    #pragma unroll
    for (int reg = 0; reg < 4; ++reg) {
      int gr = rowBase + w * 16 + quad * 4 + reg;
      partial[((size_t)blockIdx.y * 8192 + gr) * N + gc] = acc[f][reg];
    }
  }
}

// sum SPLITK partials + tanh -> bf16
__global__ __launch_bounds__(256) void reduce_tanh_kernel(
    const float* __restrict__ partial, bf16* __restrict__ out, int MN)
{
  int idx = blockIdx.x * 256 + threadIdx.x;
  float s = 0.f;
  #pragma unroll
  for (int j = 0; j < SPLITK; ++j) s += partial[(size_t)j * MN + idx];
  out[idx] = f2b(tanhf(s));
}

// ---------------------------------------------------------------------------
// VALU tiled GEMM (still used for td: M=8192,N=2048,K=64). A bf16, B fp32.
// mode: 1 tanh->bf16, 3 td = bias[n]+acc -> bf16
// ---------------------------------------------------------------------------
#define BM 128
#define BN 128
#define BKk 16

__global__ __launch_bounds__(256) void gemm_kernel(
    const bf16* __restrict__ A, const float* __restrict__ Bm,
    bf16* __restrict__ outB,
    const float* __restrict__ bias,
    int M, int N, int K, int transB, int mode)
{
  __shared__ float As[BKk][BM + 1];
  __shared__ float Bs[BKk][BN + 1];
  int tid = threadIdx.x;
  int rowBase = blockIdx.x * BM;
  int colBase = blockIdx.y * BN;
  int tx = tid & 15, ty = tid >> 4;
  float acc[8][8];
  #pragma unroll
  for (int i = 0; i < 8; ++i)
    #pragma unroll
    for (int j = 0; j < 8; ++j) acc[i][j] = 0.f;

  for (int k0 = 0; k0 < K; k0 += BKk) {
    #pragma unroll
    for (int i = 0; i < 8; ++i) {
      int lin = tid + i * 256;
      int r = lin >> 4, kk = lin & 15;
      int gr = rowBase + r, gk = k0 + kk;
      float val = 0.f;
      if (gr < M && gk < K) val = b2f(A[(size_t)gr * K + gk]);
      As[kk][r] = val;
    }
    #pragma unroll
    for (int i = 0; i < 8; ++i) {
      int lin = tid + i * 256;
      float val = 0.f;
      if (transB) {
        int n = lin >> 4, kk = lin & 15;
        int gn = colBase + n, gk = k0 + kk;
        if (gn < N && gk < K) val = Bm[(size_t)gn * K + gk];
        Bs[kk][n] = val;
      } else {
        int kk = lin >> 7, n = lin & 127;
        int gn = colBase + n, gk = k0 + kk;
        if (gn < N && gk < K) val = Bm[(size_t)gk * N + gn];
        Bs[kk][n] = val;
      }
    }
    __syncthreads();
    #pragma unroll
    for (int kk = 0; kk < BKk; ++kk) {
      float a[8], b[8];
      #pragma unroll
      for (int i = 0; i < 8; ++i) a[i] = As[kk][ty * 8 + i];
      #pragma unroll
      for (int j = 0; j < 8; ++j) b[j] = Bs[kk][tx * 8 + j];
      #pragma unroll
      for (int i = 0; i < 8; ++i)
        #pragma unroll
        for (int j = 0; j < 8; ++j)
          acc[i][j] = fmaf(a[i], b[j], acc[i][j]);
    }
    __syncthreads();
  }
  #pragma unroll
  for (int i = 0; i < 8; ++i) {
    int gr = rowBase + ty * 8 + i;
    if (gr >= M) continue;
    #pragma unroll
    for (int j = 0; j < 8; ++j) {
      int gn = colBase + tx * 8 + j;
      if (gn >= N) continue;
      float v = acc[i][j];
      size_t idx = (size_t)gr * N + gn;
      if (mode == 1)      outB[idx] = f2b(tanhf(v));
      else                outB[idx] = f2b(bias[gn] + v);   // mode 3
    }
  }
}

// ---------------------------------------------------------------------------
// K3: fused 5-way token-shift lerp via MFMA (K=32, fragments from global).
// ---------------------------------------------------------------------------
__global__ __launch_bounds__(256) void lerp5_mfma_kernel(
    const float* __restrict__ x, const bf16* __restrict__ t5,
    const bf16* __restrict__ w2t_hi, const bf16* __restrict__ w2t_lo,
    const float* __restrict__ maa_w, const float* __restrict__ maa_k,
    const float* __restrict__ maa_v, const float* __restrict__ maa_r,
    const float* __restrict__ maa_g,
    bf16* __restrict__ xd, bf16* __restrict__ xk, bf16* __restrict__ xv_,
    bf16* __restrict__ xr, bf16* __restrict__ xg)
{
  int tid  = threadIdx.x;
  int lane = tid & 63, wid = tid >> 6;
  int wm = wid & 1, wn = wid >> 1;
  int quad = lane >> 4, l16 = lane & 15;
  int rowBase = blockIdx.x * 128;
  int colBase = blockIdx.y * 128;

  const float* maas[5] = {maa_w, maa_k, maa_v, maa_r, maa_g};
  bf16* outs[5] = {xd, xk, xv_, xr, xg};

  #pragma unroll
  for (int f = 0; f < 5; ++f) {
    short8 af[4];
    #pragma unroll
    for (int i = 0; i < 4; ++i)
      af[i] = *(const short8*)(t5 +
          (size_t)(rowBase + wm * 64 + i * 16 + l16) * 160 + f * 32 + quad * 8);

    f32x4 acc[4][4];
    #pragma unroll
    for (int i = 0; i < 4; ++i)
      #pragma unroll
      for (int j = 0; j < 4; ++j)
        acc[i][j] = (f32x4){0.f, 0.f, 0.f, 0.f};

    #pragma unroll
    for (int j = 0; j < 4; ++j) {
      size_t boff = (size_t)(colBase + wn * 64 + j * 16 + l16) * 160 + f * 32 + quad * 8;
      short8 bh = *(const short8*)(w2t_hi + boff);
      short8 bl = *(const short8*)(w2t_lo + boff);
      #pragma unroll
      for (int i = 0; i < 4; ++i) {
        acc[i][j] = __builtin_amdgcn_mfma_f32_16x16x32_bf16(af[i], bh, acc[i][j], 0, 0, 0);
        acc[i][j] = __builtin_amdgcn_mfma_f32_16x16x32_bf16(af[i], bl, acc[i][j], 0, 0, 0);
      }
    }

    const float* maa = maas[f];
    bf16* outp = outs[f];
    #pragma unroll
    for (int j = 0; j < 4; ++j) {
      int gc = colBase + wn * 64 + j * 16 + l16;
      float mv = maa[gc];
      #pragma unroll
      for (int i = 0; i < 4; ++i) {
        #pragma unroll
        for (int reg = 0; reg < 4; ++reg) {
          int gr = rowBase + wm * 64 + i * 16 + quad * 4 + reg;
          size_t idx = (size_t)gr * Cc + gc;
          float xv0  = x[idx];
          float prev = ((gr & (Tt - 1)) == 0) ? 0.f : x[idx - Cc];
          outp[idx] = f2b(xv0 + (prev - xv0) * (mv + acc[i][j][reg]));
        }
      }
    }
  }
}

// ---------------------------------------------------------------------------
// K5a: chunked WKV local scan — 1 WAVE per block (no barriers).
// Thread j owns state rows n=cn*16..+16 (cn=j>>4) x cols m=mg*4..+4 (mg=j&15)
// as 16 f32x4 regs. Per step: stage k/w/v (64 ch) to LDS, read back as
// broadcast f32x4 (4+4+1 reads); next-step global loads prefetch under
// compute (no vmcnt drain — no __syncthreads in the loop).
// ---------------------------------------------------------------------------
__global__ __launch_bounds__(64) void wkv_local_kernel(
    const bf16* __restrict__ k, const bf16* __restrict__ v,
    const bf16* __restrict__ td,
    float* __restrict__ S_local, float* __restrict__ wp)
{
  int bh = blockIdx.x >> 4;          // Gg == 16
  int c  = blockIdx.x & 15;
  int b  = bh >> 5, h = bh & 31;
  int j  = threadIdx.x;              // 0..63
  int cn = j >> 4, mg = j & 15;
  __shared__ __align__(16) float kb[2][64];
  __shared__ __align__(16) float wb[2][64];
  __shared__ __align__(16) float vb[2][64];
  f32x4 s[16];
  float wpr[16];
  #pragma unroll
  for (int i = 0; i < 16; ++i) { s[i] = (f32x4){0.f,0.f,0.f,0.f}; wpr[i] = 1.f; }

  size_t base = (size_t)b * Tt * Cc + (size_t)(c * Ll) * Cc + (size_t)h * 64;
  float kv_ = b2f(k[base + j]);
  float wv_ = expf(-expf(b2f(td[base + j])));
  float vv_ = b2f(v[base + j]);
  for (int t = 0; t < Ll; ++t, base += Cc) {
    int p = t & 1;
    kb[p][j] = kv_; wb[p][j] = wv_; vb[p][j] = vv_;
    // prefetch next step (clamped to stay in-bounds; value unused at t=Ll-1)
    size_t nb = base + ((t + 1 < Ll) ? Cc : 0);
    kv_ = b2f(k[nb + j]);
    wv_ = expf(-expf(b2f(td[nb + j])));
    vv_ = b2f(v[nb + j]);
    asm volatile("s_waitcnt lgkmcnt(0)" ::: "memory");
    f32x4 vm = *(const f32x4*)(&vb[p][mg * 4]);
    #pragma unroll
    for (int i4 = 0; i4 < 4; ++i4) {
      f32x4 k4 = *(const f32x4*)(&kb[p][cn * 16 + i4 * 4]);
      f32x4 w4 = *(const f32x4*)(&wb[p][cn * 16 + i4 * 4]);
      #pragma unroll
      for (int q = 0; q < 4; ++q) {
        int i = i4 * 4 + q;
        float kn = k4[q], wn = w4[q];
        s[i].x = fmaf(wn, s[i].x, kn * vm.x);
        s[i].y = fmaf(wn, s[i].y, kn * vm.y);
        s[i].z = fmaf(wn, s[i].z, kn * vm.z);
        s[i].w = fmaf(wn, s[i].w, kn * vm.w);
        wpr[i] *= wn;
      }
    }
  }
  #pragma unroll
  for (int i = 0; i < 16; ++i)
    *(f32x4*)(&S_local[((size_t)blockIdx.x * 64 + cn * 16 + i) * 64 + mg * 4]) = s[i];
  if (mg == 0) {
    #pragma unroll
    for (int i = 0; i < 16; ++i)
      wp[blockIdx.x * 64 + cn * 16 + i] = wpr[i];
  }
}

// ---------------------------------------------------------------------------
// K5b: chunk-prefix combine over Gg=16 chunks, parallel over (b,h,n,m).
// ---------------------------------------------------------------------------
__global__ __launch_bounds__(256) void wkv_combine_kernel(
    const float* __restrict__ S_local, const float* __restrict__ wp,
    float* __restrict__ S_start)
{
  int idx = blockIdx.x * 256 + threadIdx.x;   // over B*H*N*N
  int m = idx & 63;
  int n = (idx >> 6) & 63;
  int bh = idx >> 12;
  float cur = 0.f;
  #pragma unroll
  for (int c = 0; c < Gg; ++c) {
    size_t sbase = (((size_t)(bh * Gg + c)) * 64 + n) * 64 + m;
    S_start[sbase] = cur;
    cur = fmaf(wp[(bh * Gg + c) * 64 + n], cur, S_local[sbase]);
  }
}

// ---------------------------------------------------------------------------
// K5c: chunked WKV output scan — 1 WAVE per block (no barriers), seeded from
// S_start. Same ownership as K5a plus r-broadcast, u regs, and an in-LDS
// 4-way partial reduce (b128 write + 4 b32 reads). Writes in place over td.
// ---------------------------------------------------------------------------
__global__ __launch_bounds__(64) void wkv_out_kernel(
    const bf16* __restrict__ r, const bf16* __restrict__ k,
    const bf16* __restrict__ v, const bf16* __restrict__ td,
    const float* __restrict__ u, const float* __restrict__ S_start,
    bf16* __restrict__ out)
{
  int bh = blockIdx.x >> 4;
  int c  = blockIdx.x & 15;
  int b  = bh >> 5, h = bh & 31;
  int j  = threadIdx.x;
  int cn = j >> 4, mg = j & 15;
  __shared__ __align__(16) float rb[2][64];
  __shared__ __align__(16) float kb[2][64];
  __shared__ __align__(16) float wb[2][64];
  __shared__ __align__(16) float vb[2][64];
  __shared__ __align__(16) float red[256];   // [cn][m]
  f32x4 s[16];
  float ur[16];
  #pragma unroll
  for (int i = 0; i < 16; ++i) {
    s[i]  = *(const f32x4*)(&S_start[((size_t)blockIdx.x * 64 + cn * 16 + i) * 64 + mg * 4]);
    ur[i] = u[h * 64 + cn * 16 + i];
  }

  size_t base = (size_t)b * Tt * Cc + (size_t)(c * Ll) * Cc + (size_t)h * 64;
  float rv_ = b2f(r[base + j]);
  float kv_ = b2f(k[base + j]);
  float wv_ = expf(-expf(b2f(td[base + j])));
  float vv_ = b2f(v[base + j]);
  for (int t = 0; t < Ll; ++t, base += Cc) {
    int p = t & 1;
    rb[p][j] = rv_; kb[p][j] = kv_; wb[p][j] = wv_; vb[p][j] = vv_;
    size_t nb = base + ((t + 1 < Ll) ? Cc : 0);
    rv_ = b2f(r[nb + j]);
    kv_ = b2f(k[nb + j]);
    wv_ = expf(-expf(b2f(td[nb + j])));
    vv_ = b2f(v[nb + j]);
    asm volatile("s_waitcnt lgkmcnt(0)" ::: "memory");
    f32x4 vm = *(const f32x4*)(&vb[p][mg * 4]);
    f32x4 acc = (f32x4){0.f, 0.f, 0.f, 0.f};
    #pragma unroll
    for (int i4 = 0; i4 < 4; ++i4) {
      f32x4 r4 = *(const f32x4*)(&rb[p][cn * 16 + i4 * 4]);
      f32x4 k4 = *(const f32x4*)(&kb[p][cn * 16 + i4 * 4]);
      f32x4 w4 = *(const f32x4*)(&wb[p][cn * 16 + i4 * 4]);
      #pragma unroll
      for (int q = 0; q < 4; ++q) {
        int i = i4 * 4 + q;
        float rn = r4[q], kn = k4[q], wn = w4[q], un = ur[i];
        float kvx = kn * vm.x, kvy = kn * vm.y, kvz = kn * vm.z, kvw = kn * vm.w;
        acc.x = fmaf(rn, fmaf(un, kvx, s[i].x), acc.x);
        acc.y = fmaf(rn, fmaf(un, kvy, s[i].y), acc.y);
        acc.z = fmaf(rn, fmaf(un, kvz, s[i].z), acc.z);
        acc.w = fmaf(rn, fmaf(un, kvw, s[i].w), acc.w);
        s[i].x = fmaf(wn, s[i].x, kvx);
        s[i].y = fmaf(wn, s[i].y, kvy);
        s[i].z = fmaf(wn, s[i].z, kvz);
        s[i].w = fmaf(wn, s[i].w, kvw);
      }
    }
    *(f32x4*)(&red[4 * j]) = acc;     // red[cn*64 + mg*4] == red[4*j]
    asm volatile("s_waitcnt lgkmcnt(0)" ::: "memory");
    float o = red[j] + red[64 + j] + red[128 + j] + red[192 + j];
    out[base + j] = f2b(o);
  }
}

// ---------------------------------------------------------------------------
// K6: GroupNorm over each head (N=64) + affine + gate with g
// ---------------------------------------------------------------------------
__global__ __launch_bounds__(256) void gn_gate_kernel(
    const bf16* __restrict__ wkv, const bf16* __restrict__ g,
    const float* __restrict__ lnw, const float* __restrict__ lnb,
    bf16* __restrict__ out)
{
  int bt = blockIdx.x;
  int wv = threadIdx.x >> 6, lane = threadIdx.x & 63;
  const float EPS = 6.4e-4f;   // 1e-5 * 8^2
  for (int h = wv; h < Hh; h += 4) {
    size_t base = (size_t)bt * Cc + h * 64;
    float x = b2f(wkv[base + lane]);
    float s = x, s2 = x * x;
    #pragma unroll
    for (int off = 1; off < 64; off <<= 1) {
      s  += __shfl_xor(s, off);
      s2 += __shfl_xor(s2, off);
    }
    float mean = s * (1.f / 64.f);
    float var  = s2 * (1.f / 64.f) - mean * mean;
    float inv  = rsqrtf(var + EPS);
    float normed = (x - mean) * inv * lnw[h * 64 + lane] + lnb[h * 64 + lane];
    out[base + lane] = f2b(normed * b2f(g[base + lane]));
  }
}

// ---------------------------------------------------------------------------
// Workspace map: 5 x 33.55 MB bf16 [BT,C] + 8 MB small-region + 5 x 8.39 MB
// bf16 weights ~= 218 MB. Small-region layout (offsets from ws+5*BUF):
//   +0      t5buf (2.5 MB bf16), doubles as wp (512 KB fp32) at scan time
//   +4 MB   abuf (1 MB bf16)
//   +5 MB   w1t_hi (640 KB), +5.75 MB w1t_lo (640 KB)
//   +6.5 MB dw1t_hi (256 KB), +6.75 MB dw1t_lo (256 KB)
// d_out (67 MB): bytes 0..42 MB = skinny-gemm fp32 partials (stages 2,4);
// bytes 48..49.3 MB = w2t hi/lo (consumed at stage 3); then lower half =
// bf16 r-scratch + upper half = S_local (stage 5+). S_start reuses buf0.
// ---------------------------------------------------------------------------
extern "C" void kernel_launch(void* const* d_in, const int* in_sizes, int n_in,
                              void* d_out, int out_size, void* d_ws, size_t ws_size,
                              hipStream_t stream) {
  const float* hidden = (const float*)d_in[0];
  const float* maa_x  = (const float*)d_in[1];
  const float* maa_w  = (const float*)d_in[2];
  const float* maa_k  = (const float*)d_in[3];
  const float* maa_v  = (const float*)d_in[4];
  const float* maa_r  = (const float*)d_in[5];
  const float* maa_g  = (const float*)d_in[6];
  const float* maa_w1 = (const float*)d_in[7];   // [C,160]
  const float* maa_w2 = (const float*)d_in[8];   // [160,C]
  const float* tdecay = (const float*)d_in[9];   // [C]
  const float* dw1    = (const float*)d_in[10];  // [C,64]
  const float* dw2    = (const float*)d_in[11];  // [64,C]
  const float* faaaa  = (const float*)d_in[12];  // [H,N]
  const float* w_r    = (const float*)d_in[13];
  const float* w_k    = (const float*)d_in[14];
  const float* w_v    = (const float*)d_in[15];
  const float* w_g    = (const float*)d_in[16];
  const float* w_o    = (const float*)d_in[17];
  const float* lnw    = (const float*)d_in[18];
  const float* lnb    = (const float*)d_in[19];
  float* outF = (float*)d_out;
  bf16* rscratch = (bf16*)d_out;

  char* ws = (char*)d_ws;
  const size_t BUF  = (size_t)BT * Cc * sizeof(bf16);   // 33,554,432 B
  const size_t WBUF = (size_t)Cc * Cc * sizeof(bf16);   //  8,388,608 B
  const size_t MB = 1024 * 1024;
  bf16* buf0 = (bf16*)(ws + 0 * BUF);
  bf16* buf1 = (bf16*)(ws + 1 * BUF);
  bf16* buf2 = (bf16*)(ws + 2 * BUF);
  bf16* buf3 = (bf16*)(ws + 3 * BUF);
  bf16* buf4 = (bf16*)(ws + 4 * BUF);
  char* small = ws + 5 * BUF;
  bf16* t5buf   = (bf16*)(small + 0);
  bf16* abuf    = (bf16*)(small + 4 * MB);
  bf16* w1t_hi  = (bf16*)(small + 5 * MB);
  bf16* w1t_lo  = (bf16*)(small + 5 * MB + 768 * 1024);
  bf16* dw1t_hi = (bf16*)(small + 6 * MB + 512 * 1024);
  bf16* dw1t_lo = (bf16*)(small + 6 * MB + 768 * 1024);
  char* wbase = small + 8 * MB;
  bf16* wrb = (bf16*)(wbase + 0 * WBUF);
  bf16* wkb = (bf16*)(wbase + 1 * WBUF);
  bf16* wvb = (bf16*)(wbase + 2 * WBUF);
  bf16* wgb = (bf16*)(wbase + 3 * WBUF);
  bf16* wob = (bf16*)(wbase + 4 * WBUF);

  // w2t hi/lo (640 KB each) live in d_out above the skinny partials
  bf16* w2t_hi = (bf16*)((char*)d_out + 48 * MB);
  bf16* w2t_lo = (bf16*)((char*)d_out + 49 * MB);

  // scan scratch: S_local in d_out upper half, S_start in buf0, wp in t5buf
  float* slbuf = (float*)((char*)d_out + BUF);   // 33.55 MB fp32
  float* ssbuf = (float*)buf0;                   // 33.55 MB fp32
  float* wpbuf = (float*)t5buf;                  // 512 KB fp32
  // skinny-gemm partial scratch: d_out bytes 0..42 MB (free until stage 5)
  float* pbuf  = (float*)d_out;

  dim3 blk(256);
  const int CVT_G = Cc * Cc / 256;   // 16384

  // 0. weight conversions (independent of data pipeline)
  cvt_kernel<<<dim3(CVT_G), blk, 0, stream>>>(w_r, wrb);
  cvt_kernel<<<dim3(CVT_G), blk, 0, stream>>>(w_k, wkb);
  cvt_kernel<<<dim3(CVT_G), blk, 0, stream>>>(w_v, wvb);
  cvt_kernel<<<dim3(CVT_G), blk, 0, stream>>>(w_g, wgb);
  cvt_kernel<<<dim3(CVT_G), blk, 0, stream>>>(w_o, wob);
  cvt_t2_kernel<<<dim3(160 * Cc / 256), blk, 0, stream>>>(maa_w1, w1t_hi, w1t_lo, 160);
  cvt_t2_kernel<<<dim3(64 * Cc / 256), blk, 0, stream>>>(dw1, dw1t_hi, dw1t_lo, 64);
  cvt_w2t_kernel<<<dim3(160 * Cc / 256), blk, 0, stream>>>(maa_w2, w2t_hi, w2t_lo);

  // 1. xm -> buf0
  prep_xm_kernel<<<dim3(BT * Cc / 256), blk, 0, stream>>>(hidden, maa_x, buf0);

  // 2. t5 = tanh(xm @ maa_w1): M=8192,N=160,K=2048 via split-K MFMA (hi/lo)
  mfma_skinny_kernel<10><<<dim3(128, SPLITK), blk, 0, stream>>>(
      buf0, w1t_hi, w1t_lo, pbuf, 2048 / SPLITK);
  reduce_tanh_kernel<<<dim3(BT * 160 / 256), blk, 0, stream>>>(pbuf, t5buf,
                                                               BT * 160);

  // 3. fused lerp (MFMA) -> xd(1) xk(2) xv(3) xr(4) xg(0)
  lerp5_mfma_kernel<<<dim3(64, 16), blk, 0, stream>>>(hidden, t5buf,
      w2t_hi, w2t_lo, maa_w, maa_k, maa_v, maa_r, maa_g,
      buf1, buf2, buf3, buf4, buf0);

  // 4. decay: a = tanh(xd @ dw1) [8192,64] via split-K MFMA (hi/lo);
  //    td = tdecay + a @ dw2 -> buf1 (VALU gemm, K=64)
  mfma_skinny_kernel<4><<<dim3(128, SPLITK), blk, 0, stream>>>(
      buf1, dw1t_hi, dw1t_lo, pbuf, 2048 / SPLITK);
  reduce_tanh_kernel<<<dim3(BT * 64 / 256), blk, 0, stream>>>(pbuf, abuf,
                                                              BT * 64);
  gemm_kernel<<<dim3(64, 16), blk, 0, stream>>>(abuf, dw2, buf1, tdecay,
                                                BT, Cc, 64, 0, 3);

  // 5. projections (MFMA): r->rscratch, k->buf4, v->buf2, g(silu)->buf3
  mfma_gemm_kernel<<<dim3(64, 16), blk, 0, stream>>>(buf4, wrb, rscratch, nullptr, 0);
  mfma_gemm_kernel<<<dim3(64, 16), blk, 0, stream>>>(buf2, wkb, buf4, nullptr, 0);
  mfma_gemm_kernel<<<dim3(64, 16), blk, 0, stream>>>(buf3, wvb, buf2, nullptr, 0);
  mfma_gemm_kernel<<<dim3(64, 16), blk, 0, stream>>>(buf0, wgb, buf3, nullptr, 2);

  // 6. chunked WKV scan: r=rscratch, k=buf4, v=buf2, td=buf1 -> out over buf1
  wkv_local_kernel<<<dim3(Bb * Hh * Gg), dim3(64), 0, stream>>>(
      buf4, buf2, buf1, slbuf, wpbuf);
  wkv_combine_kernel<<<dim3(Bb * Hh * Nn * Nn / 256), blk, 0, stream>>>(
      slbuf, wpbuf, ssbuf);
  wkv_out_kernel<<<dim3(Bb * Hh * Gg), dim3(64), 0, stream>>>(
      rscratch, buf4, buf2, buf1, faaaa, ssbuf, buf1);

  // 7. GroupNorm + gate -> buf4 (wkv out now lives in buf1)
  gn_gate_kernel<<<dim3(BT), blk, 0, stream>>>(buf1, buf3, lnw, lnb, buf4);

  // 8. final projection (MFMA) -> d_out fp32
  mfma_gemm_kernel<<<dim3(64, 16), blk, 0, stream>>>(buf4, wob, nullptr, outF, 4);
}

// Round 7
// 1574.428 us; speedup vs baseline: 1.2279x; 1.1211x over previous
//
#include <hip/hip_runtime.h>
#include <hip/hip_bf16.h>
#include <math.h>

typedef __hip_bfloat16 bf16;
typedef __attribute__((ext_vector_type(8))) short short8;   // 8 bf16 = 4 VGPRs
typedef __attribute__((ext_vector_type(4))) float f32x4;

#define Bb 4
#define Tt 2048
#define Cc 2048
#define Hh 32
#define Nn 64
#define BT (Bb*Tt)   // 8192
#define Gg 16        // scan chunks per (b,h)
#define Ll 128       // timesteps per chunk (Gg*Ll == Tt)
#define SPLITK 8     // K-split for skinny MFMA gemms

__device__ __forceinline__ float b2f(bf16 x) { return __bfloat162float(x); }
__device__ __forceinline__ bf16  f2b(float x) { return __float2bfloat16(x); }

// async global->LDS DMA, 16B per lane (wave-uniform LDS base + lane*16)
__device__ __forceinline__ void gload16(const bf16* g, bf16* l) {
  __builtin_amdgcn_global_load_lds(
      (const __attribute__((address_space(1))) void*)g,
      (__attribute__((address_space(3))) void*)l, 16, 0, 0);
}

// ---------------------------------------------------------------------------
// K0: fp32 -> bf16 weight conversion (for MFMA GEMMs)
// ---------------------------------------------------------------------------
__global__ __launch_bounds__(256) void cvt_kernel(
    const float* __restrict__ in, bf16* __restrict__ out)
{
  int i = blockIdx.x * 256 + threadIdx.x;
  out[i] = f2b(in[i]);
}

// ---------------------------------------------------------------------------
// K0b: fp32 [K,N] -> bf16 hi/lo [N,K] transpose-convert (K == 2048 fixed).
// hi = bf16(w); lo = bf16(w - hi). Two-MFMA accumulation recovers ~fp32 B.
// ---------------------------------------------------------------------------
__global__ __launch_bounds__(256) void cvt_t2_kernel(
    const float* __restrict__ in, bf16* __restrict__ hi, bf16* __restrict__ lo,
    int N)
{
  int idx = blockIdx.x * 256 + threadIdx.x;   // over N*2048
  int n = idx >> 11, k = idx & 2047;
  float v = in[(size_t)k * N + n];
  bf16 h = f2b(v);
  hi[idx] = h;
  lo[idx] = f2b(v - b2f(h));
}

// ---------------------------------------------------------------------------
// K0c: w2 fp32 [160, C] -> bf16 hi/lo [C, 160] transpose-convert.
// ---------------------------------------------------------------------------
__global__ __launch_bounds__(256) void cvt_w2t_kernel(
    const float* __restrict__ in, bf16* __restrict__ hi, bf16* __restrict__ lo)
{
  int idx = blockIdx.x * 256 + threadIdx.x;   // over 2048*160
  int c = idx / 160, e = idx - c * 160;
  float v = in[(size_t)e * Cc + c];
  bf16 h = f2b(v);
  hi[idx] = h;
  lo[idx] = f2b(v - b2f(h));
}

// ---------------------------------------------------------------------------
// K1: xm = x + (shift(x) - x) * time_maa_x
// ---------------------------------------------------------------------------
__global__ __launch_bounds__(256) void prep_xm_kernel(
    const float* __restrict__ x, const float* __restrict__ maa_x,
    bf16* __restrict__ xm)
{
  int idx = blockIdx.x * 256 + threadIdx.x;
  int c  = idx & (Cc - 1);
  int bt = idx >> 11;
  int t  = bt & (Tt - 1);
  float xv   = x[idx];
  float prev = (t == 0) ? 0.f : x[idx - Cc];
  xm[idx] = f2b(xv + (prev - xv) * maa_x[c]);
}

// ---------------------------------------------------------------------------
// MFMA GEMM (m97 structure + XOR swizzle BOTH sides, rule #21):
// C[8192,2048] = A * B^T. 128x128 tile, BK=32, linear LDS [128][32] staged
// via global_load_lds dwordx4. Swizzle: LDS(row,blk) holds global
// (row, blk ^ ((row&15)>>1 & 3)) — achieved by pre-swizzling the per-lane
// GLOBAL source (DMA dest is lane-linear, can't scatter); ds_read applies
// the same XOR. Even/odd rows then hit 4 distinct 16B slots per bank-half
// -> 2-way conflict (free). R5's linear version was 8-way (regressed).
// mode: 0 plain->bf16, 2 silu->bf16, 4 plain->fp32
// ---------------------------------------------------------------------------
__global__ __launch_bounds__(256) void mfma_gemm_kernel(
    const bf16* __restrict__ A, const bf16* __restrict__ B,
    bf16* __restrict__ outB, float* __restrict__ outF, int mode)
{
  __shared__ __align__(16) bf16 As[128 * 32];
  __shared__ __align__(16) bf16 Bs[128 * 32];
  int tid  = threadIdx.x;
  int lane = tid & 63, wid = tid >> 6;
  int wm = wid & 1, wn = wid >> 1;
  int quad = lane >> 4, l16 = lane & 15;
  size_t rowBase = (size_t)blockIdx.x * 128;
  size_t colBase = (size_t)blockIdx.y * 128;

  // staging: 16 KB/iter = 16 segs of 1KB; wave w does A-segs {2w,2w+1} and
  // B-segs {2w,2w+1}. lane i -> LDS row seg*16+(i>>2), blk i&3 (linear);
  // global col-block pre-swizzled: (i&3) ^ ((i>>2 >>1)&3).
  int seg0 = wid * 2, seg1 = seg0 + 1;
  int lrow = lane >> 2;
  int cb = (((lane & 3) ^ ((lrow >> 1) & 3))) * 8;
  const bf16* ga0 = A + (rowBase + seg0 * 16 + lrow) * 2048 + cb;
  const bf16* ga1 = A + (rowBase + seg1 * 16 + lrow) * 2048 + cb;
  const bf16* gb0 = B + (colBase + seg0 * 16 + lrow) * 2048 + cb;
  const bf16* gb1 = B + (colBase + seg1 * 16 + lrow) * 2048 + cb;

  f32x4 acc[4][4];
  #pragma unroll
  for (int i = 0; i < 4; ++i)
    #pragma unroll
    for (int j = 0; j < 4; ++j)
      acc[i][j] = (f32x4){0.f, 0.f, 0.f, 0.f};

  int fsw = ((l16 >> 1) & 3) * 8;   // read-side XOR (elems)
  for (int k0 = 0; k0 < 2048; k0 += 32) {
    gload16(ga0 + k0, As + seg0 * 512);
    gload16(ga1 + k0, As + seg1 * 512);
    gload16(gb0 + k0, Bs + seg0 * 512);
    gload16(gb1 + k0, Bs + seg1 * 512);
    __syncthreads();            // drains vmcnt(0) before s_barrier
    short8 af[4], bf[4];
    #pragma unroll
    for (int i = 0; i < 4; ++i) {
      af[i] = *(const short8*)(As + (wm * 64 + i * 16 + l16) * 32 + ((quad * 8) ^ fsw));
      bf[i] = *(const short8*)(Bs + (wn * 64 + i * 16 + l16) * 32 + ((quad * 8) ^ fsw));
    }
    #pragma unroll
    for (int i = 0; i < 4; ++i)
      #pragma unroll
      for (int j = 0; j < 4; ++j)
        acc[i][j] = __builtin_amdgcn_mfma_f32_16x16x32_bf16(af[i], bf[j], acc[i][j], 0, 0, 0);
    __syncthreads();
  }

  #pragma unroll
  for (int i = 0; i < 4; ++i) {
    #pragma unroll
    for (int j = 0; j < 4; ++j) {
      int gc = colBase + wn * 64 + j * 16 + l16;
      #pragma unroll
      for (int reg = 0; reg < 4; ++reg) {
        int gr = rowBase + wm * 64 + i * 16 + quad * 4 + reg;
        float v = acc[i][j][reg];
        size_t idx = (size_t)gr * 2048 + gc;
        if (mode == 0)      outB[idx] = f2b(v);
        else if (mode == 2) outB[idx] = f2b(v / (1.f + expf(-v)));
        else                outF[idx] = v;
      }
    }
  }
}

// ---------------------------------------------------------------------------
// Skinny MFMA GEMM with split-K and hi/lo B compensation:
// C_partial[kseg][8192][N] = A_seg @ (Bhi+Blo)_seg^T.
// ---------------------------------------------------------------------------
#define LDA 40   // padded LDS row for VALU-staged tiles

template<int NF>
__global__ __launch_bounds__(256) void mfma_skinny_kernel(
    const bf16* __restrict__ A, const bf16* __restrict__ Bt_hi,
    const bf16* __restrict__ Bt_lo,
    float* __restrict__ partial, int kseg_len)
{
  constexpr int N = NF * 16;
  __shared__ bf16 As[64 * LDA];
  __shared__ bf16 Bs[2 * N * LDA];   // rows 0..N-1 hi, N..2N-1 lo
  int tid = threadIdx.x;
  int lane = tid & 63, w = tid >> 6;
  int quad = lane >> 4, l16 = lane & 15;
  int rowBase = blockIdx.x * 64;
  int kbeg = blockIdx.y * kseg_len;

  f32x4 acc[NF];
  #pragma unroll
  for (int f = 0; f < NF; ++f) acc[f] = (f32x4){0.f, 0.f, 0.f, 0.f};

  for (int k0 = kbeg; k0 < kbeg + kseg_len; k0 += 32) {
    {
      int row = tid >> 2, kc = (tid & 3) * 8;
      *(short8*)(As + row * LDA + kc) =
          *(const short8*)(A + (size_t)(rowBase + row) * 2048 + k0 + kc);
    }
    for (int c = tid; c < N * 8; c += 256) {
      int half = c >= N * 4;
      int cc = c - half * N * 4;
      int row = cc >> 2, kc = (cc & 3) * 8;
      const bf16* src = half ? Bt_lo : Bt_hi;
      *(short8*)(Bs + (half * N + row) * LDA + kc) =
          *(const short8*)(src + (size_t)row * 2048 + k0 + kc);
    }
    __syncthreads();
    short8 af = *(const short8*)(As + (w * 16 + l16) * LDA + quad * 8);
    #pragma unroll
    for (int f = 0; f < NF; ++f) {
      short8 bh = *(const short8*)(Bs + (f * 16 + l16) * LDA + quad * 8);
      short8 bl = *(const short8*)(Bs + ((N + f * 16 + l16)) * LDA + quad * 8);
      acc[f] = __builtin_amdgcn_mfma_f32_16x16x32_bf16(af, bh, acc[f], 0, 0, 0);
      acc[f] = __builtin_amdgcn_mfma_f32_16x16x32_bf16(af, bl, acc[f], 0, 0, 0);
    }
    __syncthreads();
  }

  #pragma unroll
  for (int f = 0; f < NF; ++f) {
    int gc = f * 16 + l16;
    #pragma unroll
    for (int reg = 0; reg < 4; ++reg) {
      int gr = rowBase + w * 16 + quad * 4 + reg;
      partial[((size_t)blockIdx.y * 8192 + gr) * N + gc] = acc[f][reg];
    }
  }
}

// sum SPLITK partials + tanh -> bf16
__global__ __launch_bounds__(256) void reduce_tanh_kernel(
    const float* __restrict__ partial, bf16* __restrict__ out, int MN)
{
  int idx = blockIdx.x * 256 + threadIdx.x;
  float s = 0.f;
  #pragma unroll
  for (int j = 0; j < SPLITK; ++j) s += partial[(size_t)j * MN + idx];
  out[idx] = f2b(tanhf(s));
}

// ---------------------------------------------------------------------------
// VALU tiled GEMM (still used for td: M=8192,N=2048,K=64). A bf16, B fp32.
// mode: 1 tanh->bf16, 3 td = bias[n]+acc -> bf16
// ---------------------------------------------------------------------------
#define BM 128
#define BN 128
#define BKk 16

__global__ __launch_bounds__(256) void gemm_kernel(
    const bf16* __restrict__ A, const float* __restrict__ Bm,
    bf16* __restrict__ outB,
    const float* __restrict__ bias,
    int M, int N, int K, int transB, int mode)
{
  __shared__ float As[BKk][BM + 1];
  __shared__ float Bs[BKk][BN + 1];
  int tid = threadIdx.x;
  int rowBase = blockIdx.x * BM;
  int colBase = blockIdx.y * BN;
  int tx = tid & 15, ty = tid >> 4;
  float acc[8][8];
  #pragma unroll
  for (int i = 0; i < 8; ++i)
    #pragma unroll
    for (int j = 0; j < 8; ++j) acc[i][j] = 0.f;

  for (int k0 = 0; k0 < K; k0 += BKk) {
    #pragma unroll
    for (int i = 0; i < 8; ++i) {
      int lin = tid + i * 256;
      int r = lin >> 4, kk = lin & 15;
      int gr = rowBase + r, gk = k0 + kk;
      float val = 0.f;
      if (gr < M && gk < K) val = b2f(A[(size_t)gr * K + gk]);
      As[kk][r] = val;
    }
    #pragma unroll
    for (int i = 0; i < 8; ++i) {
      int lin = tid + i * 256;
      float val = 0.f;
      if (transB) {
        int n = lin >> 4, kk = lin & 15;
        int gn = colBase + n, gk = k0 + kk;
        if (gn < N && gk < K) val = Bm[(size_t)gn * K + gk];
        Bs[kk][n] = val;
      } else {
        int kk = lin >> 7, n = lin & 127;
        int gn = colBase + n, gk = k0 + kk;
        if (gn < N && gk < K) val = Bm[(size_t)gk * N + gn];
        Bs[kk][n] = val;
      }
    }
    __syncthreads();
    #pragma unroll
    for (int kk = 0; kk < BKk; ++kk) {
      float a[8], b[8];
      #pragma unroll
      for (int i = 0; i < 8; ++i) a[i] = As[kk][ty * 8 + i];
      #pragma unroll
      for (int j = 0; j < 8; ++j) b[j] = Bs[kk][tx * 8 + j];
      #pragma unroll
      for (int i = 0; i < 8; ++i)
        #pragma unroll
        for (int j = 0; j < 8; ++j)
          acc[i][j] = fmaf(a[i], b[j], acc[i][j]);
    }
    __syncthreads();
  }
  #pragma unroll
  for (int i = 0; i < 8; ++i) {
    int gr = rowBase + ty * 8 + i;
    if (gr >= M) continue;
    #pragma unroll
    for (int j = 0; j < 8; ++j) {
      int gn = colBase + tx * 8 + j;
      if (gn >= N) continue;
      float v = acc[i][j];
      size_t idx = (size_t)gr * N + gn;
      if (mode == 1)      outB[idx] = f2b(tanhf(v));
      else                outB[idx] = f2b(bias[gn] + v);   // mode 3
    }
  }
}

// ---------------------------------------------------------------------------
// K3: fused 5-way token-shift lerp via MFMA, j-OUTER: per column-fragment j,
// run all 5 f's MFMAs into accJ[5][4] (statically indexed), then ONE
// epilogue pass loading x once per position and emitting all 5 outputs.
// x scalar loads drop 5x vs f-outer (R6: 427 MB HBM, latency-bound at 11%
// occupancy / 212 VGPR).
// ---------------------------------------------------------------------------
__global__ __launch_bounds__(256) void lerp5_mfma_kernel(
    const float* __restrict__ x, const bf16* __restrict__ t5,
    const bf16* __restrict__ w2t_hi, const bf16* __restrict__ w2t_lo,
    const float* __restrict__ maa_w, const float* __restrict__ maa_k,
    const float* __restrict__ maa_v, const float* __restrict__ maa_r,
    const float* __restrict__ maa_g,
    bf16* __restrict__ xd, bf16* __restrict__ xk, bf16* __restrict__ xv_,
    bf16* __restrict__ xr, bf16* __restrict__ xg)
{
  int tid  = threadIdx.x;
  int lane = tid & 63, wid = tid >> 6;
  int wm = wid & 1, wn = wid >> 1;
  int quad = lane >> 4, l16 = lane & 15;
  int rowBase = blockIdx.x * 128;
  int colBase = blockIdx.y * 128;

  const float* maas[5] = {maa_w, maa_k, maa_v, maa_r, maa_g};
  bf16* outs[5] = {xd, xk, xv_, xr, xg};

  #pragma unroll
  for (int j = 0; j < 4; ++j) {
    int gc = colBase + wn * 64 + j * 16 + l16;
    f32x4 accJ[5][4];
    #pragma unroll
    for (int f = 0; f < 5; ++f)
      #pragma unroll
      for (int i = 0; i < 4; ++i)
        accJ[f][i] = (f32x4){0.f, 0.f, 0.f, 0.f};

    #pragma unroll
    for (int f = 0; f < 5; ++f) {
      size_t boff = (size_t)gc * 160 + f * 32 + quad * 8;
      short8 bh = *(const short8*)(w2t_hi + boff);
      short8 bl = *(const short8*)(w2t_lo + boff);
      #pragma unroll
      for (int i = 0; i < 4; ++i) {
        short8 af = *(const short8*)(t5 +
            (size_t)(rowBase + wm * 64 + i * 16 + l16) * 160 + f * 32 + quad * 8);
        accJ[f][i] = __builtin_amdgcn_mfma_f32_16x16x32_bf16(af, bh, accJ[f][i], 0, 0, 0);
        accJ[f][i] = __builtin_amdgcn_mfma_f32_16x16x32_bf16(af, bl, accJ[f][i], 0, 0, 0);
      }
    }

    float mv[5];
    #pragma unroll
    for (int f = 0; f < 5; ++f) mv[f] = maas[f][gc];

    #pragma unroll
    for (int i = 0; i < 4; ++i) {
      #pragma unroll
      for (int reg = 0; reg < 4; ++reg) {
        int gr = rowBase + wm * 64 + i * 16 + quad * 4 + reg;
        size_t idx = (size_t)gr * Cc + gc;
        float xv0  = x[idx];
        float prev = ((gr & (Tt - 1)) == 0) ? 0.f : x[idx - Cc];
        float xx = prev - xv0;
        #pragma unroll
        for (int f = 0; f < 5; ++f)
          outs[f][idx] = f2b(xv0 + xx * (mv[f] + accJ[f][i][reg]));
      }
    }
  }
}

// ---------------------------------------------------------------------------
// K5a: chunked WKV local scan — 1 WAVE per block (no barriers).
// ---------------------------------------------------------------------------
__global__ __launch_bounds__(64) void wkv_local_kernel(
    const bf16* __restrict__ k, const bf16* __restrict__ v,
    const bf16* __restrict__ td,
    float* __restrict__ S_local, float* __restrict__ wp)
{
  int bh = blockIdx.x >> 4;          // Gg == 16
  int c  = blockIdx.x & 15;
  int b  = bh >> 5, h = bh & 31;
  int j  = threadIdx.x;              // 0..63
  int cn = j >> 4, mg = j & 15;
  __shared__ __align__(16) float kb[2][64];
  __shared__ __align__(16) float wb[2][64];
  __shared__ __align__(16) float vb[2][64];
  f32x4 s[16];
  float wpr[16];
  #pragma unroll
  for (int i = 0; i < 16; ++i) { s[i] = (f32x4){0.f,0.f,0.f,0.f}; wpr[i] = 1.f; }

  size_t base = (size_t)b * Tt * Cc + (size_t)(c * Ll) * Cc + (size_t)h * 64;
  float kv_ = b2f(k[base + j]);
  float wv_ = expf(-expf(b2f(td[base + j])));
  float vv_ = b2f(v[base + j]);
  for (int t = 0; t < Ll; ++t, base += Cc) {
    int p = t & 1;
    kb[p][j] = kv_; wb[p][j] = wv_; vb[p][j] = vv_;
    size_t nb = base + ((t + 1 < Ll) ? Cc : 0);
    kv_ = b2f(k[nb + j]);
    wv_ = expf(-expf(b2f(td[nb + j])));
    vv_ = b2f(v[nb + j]);
    asm volatile("s_waitcnt lgkmcnt(0)" ::: "memory");
    f32x4 vm = *(const f32x4*)(&vb[p][mg * 4]);
    #pragma unroll
    for (int i4 = 0; i4 < 4; ++i4) {
      f32x4 k4 = *(const f32x4*)(&kb[p][cn * 16 + i4 * 4]);
      f32x4 w4 = *(const f32x4*)(&wb[p][cn * 16 + i4 * 4]);
      #pragma unroll
      for (int q = 0; q < 4; ++q) {
        int i = i4 * 4 + q;
        float kn = k4[q], wn = w4[q];
        s[i].x = fmaf(wn, s[i].x, kn * vm.x);
        s[i].y = fmaf(wn, s[i].y, kn * vm.y);
        s[i].z = fmaf(wn, s[i].z, kn * vm.z);
        s[i].w = fmaf(wn, s[i].w, kn * vm.w);
        wpr[i] *= wn;
      }
    }
  }
  #pragma unroll
  for (int i = 0; i < 16; ++i)
    *(f32x4*)(&S_local[((size_t)blockIdx.x * 64 + cn * 16 + i) * 64 + mg * 4]) = s[i];
  if (mg == 0) {
    #pragma unroll
    for (int i = 0; i < 16; ++i)
      wp[blockIdx.x * 64 + cn * 16 + i] = wpr[i];
  }
}

// ---------------------------------------------------------------------------
// K5b: chunk-prefix combine over Gg=16 chunks, parallel over (b,h,n,m).
// ---------------------------------------------------------------------------
__global__ __launch_bounds__(256) void wkv_combine_kernel(
    const float* __restrict__ S_local, const float* __restrict__ wp,
    float* __restrict__ S_start)
{
  int idx = blockIdx.x * 256 + threadIdx.x;   // over B*H*N*N
  int m = idx & 63;
  int n = (idx >> 6) & 63;
  int bh = idx >> 12;
  float cur = 0.f;
  #pragma unroll
  for (int c = 0; c < Gg; ++c) {
    size_t sbase = (((size_t)(bh * Gg + c)) * 64 + n) * 64 + m;
    S_start[sbase] = cur;
    cur = fmaf(wp[(bh * Gg + c) * 64 + n], cur, S_local[sbase]);
  }
}

// ---------------------------------------------------------------------------
// K5c: chunked WKV output scan — 1 WAVE per block (no barriers), seeded from
// S_start. Writes in place over td.
// ---------------------------------------------------------------------------
__global__ __launch_bounds__(64) void wkv_out_kernel(
    const bf16* __restrict__ r, const bf16* __restrict__ k,
    const bf16* __restrict__ v, const bf16* __restrict__ td,
    const float* __restrict__ u, const float* __restrict__ S_start,
    bf16* __restrict__ out)
{
  int bh = blockIdx.x >> 4;
  int c  = blockIdx.x & 15;
  int b  = bh >> 5, h = bh & 31;
  int j  = threadIdx.x;
  int cn = j >> 4, mg = j & 15;
  __shared__ __align__(16) float rb[2][64];
  __shared__ __align__(16) float kb[2][64];
  __shared__ __align__(16) float wb[2][64];
  __shared__ __align__(16) float vb[2][64];
  __shared__ __align__(16) float red[256];   // [cn][m]
  f32x4 s[16];
  float ur[16];
  #pragma unroll
  for (int i = 0; i < 16; ++i) {
    s[i]  = *(const f32x4*)(&S_start[((size_t)blockIdx.x * 64 + cn * 16 + i) * 64 + mg * 4]);
    ur[i] = u[h * 64 + cn * 16 + i];
  }

  size_t base = (size_t)b * Tt * Cc + (size_t)(c * Ll) * Cc + (size_t)h * 64;
  float rv_ = b2f(r[base + j]);
  float kv_ = b2f(k[base + j]);
  float wv_ = expf(-expf(b2f(td[base + j])));
  float vv_ = b2f(v[base + j]);
  for (int t = 0; t < Ll; ++t, base += Cc) {
    int p = t & 1;
    rb[p][j] = rv_; kb[p][j] = kv_; wb[p][j] = wv_; vb[p][j] = vv_;
    size_t nb = base + ((t + 1 < Ll) ? Cc : 0);
    rv_ = b2f(r[nb + j]);
    kv_ = b2f(k[nb + j]);
    wv_ = expf(-expf(b2f(td[nb + j])));
    vv_ = b2f(v[nb + j]);
    asm volatile("s_waitcnt lgkmcnt(0)" ::: "memory");
    f32x4 vm = *(const f32x4*)(&vb[p][mg * 4]);
    f32x4 acc = (f32x4){0.f, 0.f, 0.f, 0.f};
    #pragma unroll
    for (int i4 = 0; i4 < 4; ++i4) {
      f32x4 r4 = *(const f32x4*)(&rb[p][cn * 16 + i4 * 4]);
      f32x4 k4 = *(const f32x4*)(&kb[p][cn * 16 + i4 * 4]);
      f32x4 w4 = *(const f32x4*)(&wb[p][cn * 16 + i4 * 4]);
      #pragma unroll
      for (int q = 0; q < 4; ++q) {
        int i = i4 * 4 + q;
        float rn = r4[q], kn = k4[q], wn = w4[q], un = ur[i];
        float kvx = kn * vm.x, kvy = kn * vm.y, kvz = kn * vm.z, kvw = kn * vm.w;
        acc.x = fmaf(rn, fmaf(un, kvx, s[i].x), acc.x);
        acc.y = fmaf(rn, fmaf(un, kvy, s[i].y), acc.y);
        acc.z = fmaf(rn, fmaf(un, kvz, s[i].z), acc.z);
        acc.w = fmaf(rn, fmaf(un, kvw, s[i].w), acc.w);
        s[i].x = fmaf(wn, s[i].x, kvx);
        s[i].y = fmaf(wn, s[i].y, kvy);
        s[i].z = fmaf(wn, s[i].z, kvz);
        s[i].w = fmaf(wn, s[i].w, kvw);
      }
    }
    *(f32x4*)(&red[4 * j]) = acc;     // red[cn*64 + mg*4] == red[4*j]
    asm volatile("s_waitcnt lgkmcnt(0)" ::: "memory");
    float o = red[j] + red[64 + j] + red[128 + j] + red[192 + j];
    out[base + j] = f2b(o);
  }
}

// ---------------------------------------------------------------------------
// K6: GroupNorm over each head (N=64) + affine + gate with g
// ---------------------------------------------------------------------------
__global__ __launch_bounds__(256) void gn_gate_kernel(
    const bf16* __restrict__ wkv, const bf16* __restrict__ g,
    const float* __restrict__ lnw, const float* __restrict__ lnb,
    bf16* __restrict__ out)
{
  int bt = blockIdx.x;
  int wv = threadIdx.x >> 6, lane = threadIdx.x & 63;
  const float EPS = 6.4e-4f;   // 1e-5 * 8^2
  for (int h = wv; h < Hh; h += 4) {
    size_t base = (size_t)bt * Cc + h * 64;
    float x = b2f(wkv[base + lane]);
    float s = x, s2 = x * x;
    #pragma unroll
    for (int off = 1; off < 64; off <<= 1) {
      s  += __shfl_xor(s, off);
      s2 += __shfl_xor(s2, off);
    }
    float mean = s * (1.f / 64.f);
    float var  = s2 * (1.f / 64.f) - mean * mean;
    float inv  = rsqrtf(var + EPS);
    float normed = (x - mean) * inv * lnw[h * 64 + lane] + lnb[h * 64 + lane];
    out[base + lane] = f2b(normed * b2f(g[base + lane]));
  }
}

// ---------------------------------------------------------------------------
// Workspace map: 5 x 33.55 MB bf16 [BT,C] + 8 MB small-region + 5 x 8.39 MB
// bf16 weights ~= 218 MB. Small-region layout (offsets from ws+5*BUF):
//   +0      t5buf (2.5 MB bf16), doubles as wp (512 KB fp32) at scan time
//   +4 MB   abuf (1 MB bf16)
//   +5 MB   w1t_hi (640 KB), +5.75 MB w1t_lo (640 KB)
//   +6.5 MB dw1t_hi (256 KB), +6.75 MB dw1t_lo (256 KB)
// d_out (67 MB): bytes 0..42 MB = skinny-gemm fp32 partials (stages 2,4);
// bytes 48..49.3 MB = w2t hi/lo (consumed at stage 3); then lower half =
// bf16 r-scratch + upper half = S_local (stage 5+). S_start reuses buf0.
// ---------------------------------------------------------------------------
extern "C" void kernel_launch(void* const* d_in, const int* in_sizes, int n_in,
                              void* d_out, int out_size, void* d_ws, size_t ws_size,
                              hipStream_t stream) {
  const float* hidden = (const float*)d_in[0];
  const float* maa_x  = (const float*)d_in[1];
  const float* maa_w  = (const float*)d_in[2];
  const float* maa_k  = (const float*)d_in[3];
  const float* maa_v  = (const float*)d_in[4];
  const float* maa_r  = (const float*)d_in[5];
  const float* maa_g  = (const float*)d_in[6];
  const float* maa_w1 = (const float*)d_in[7];   // [C,160]
  const float* maa_w2 = (const float*)d_in[8];   // [160,C]
  const float* tdecay = (const float*)d_in[9];   // [C]
  const float* dw1    = (const float*)d_in[10];  // [C,64]
  const float* dw2    = (const float*)d_in[11];  // [64,C]
  const float* faaaa  = (const float*)d_in[12];  // [H,N]
  const float* w_r    = (const float*)d_in[13];
  const float* w_k    = (const float*)d_in[14];
  const float* w_v    = (const float*)d_in[15];
  const float* w_g    = (const float*)d_in[16];
  const float* w_o    = (const float*)d_in[17];
  const float* lnw    = (const float*)d_in[18];
  const float* lnb    = (const float*)d_in[19];
  float* outF = (float*)d_out;
  bf16* rscratch = (bf16*)d_out;

  char* ws = (char*)d_ws;
  const size_t BUF  = (size_t)BT * Cc * sizeof(bf16);   // 33,554,432 B
  const size_t WBUF = (size_t)Cc * Cc * sizeof(bf16);   //  8,388,608 B
  const size_t MB = 1024 * 1024;
  bf16* buf0 = (bf16*)(ws + 0 * BUF);
  bf16* buf1 = (bf16*)(ws + 1 * BUF);
  bf16* buf2 = (bf16*)(ws + 2 * BUF);
  bf16* buf3 = (bf16*)(ws + 3 * BUF);
  bf16* buf4 = (bf16*)(ws + 4 * BUF);
  char* small = ws + 5 * BUF;
  bf16* t5buf   = (bf16*)(small + 0);
  bf16* abuf    = (bf16*)(small + 4 * MB);
  bf16* w1t_hi  = (bf16*)(small + 5 * MB);
  bf16* w1t_lo  = (bf16*)(small + 5 * MB + 768 * 1024);
  bf16* dw1t_hi = (bf16*)(small + 6 * MB + 512 * 1024);
  bf16* dw1t_lo = (bf16*)(small + 6 * MB + 768 * 1024);
  char* wbase = small + 8 * MB;
  bf16* wrb = (bf16*)(wbase + 0 * WBUF);
  bf16* wkb = (bf16*)(wbase + 1 * WBUF);
  bf16* wvb = (bf16*)(wbase + 2 * WBUF);
  bf16* wgb = (bf16*)(wbase + 3 * WBUF);
  bf16* wob = (bf16*)(wbase + 4 * WBUF);

  // w2t hi/lo (640 KB each) live in d_out above the skinny partials
  bf16* w2t_hi = (bf16*)((char*)d_out + 48 * MB);
  bf16* w2t_lo = (bf16*)((char*)d_out + 49 * MB);

  // scan scratch: S_local in d_out upper half, S_start in buf0, wp in t5buf
  float* slbuf = (float*)((char*)d_out + BUF);   // 33.55 MB fp32
  float* ssbuf = (float*)buf0;                   // 33.55 MB fp32
  float* wpbuf = (float*)t5buf;                  // 512 KB fp32
  // skinny-gemm partial scratch: d_out bytes 0..42 MB (free until stage 5)
  float* pbuf  = (float*)d_out;

  dim3 blk(256);
  const int CVT_G = Cc * Cc / 256;   // 16384

  // 0. weight conversions (independent of data pipeline)
  cvt_kernel<<<dim3(CVT_G), blk, 0, stream>>>(w_r, wrb);
  cvt_kernel<<<dim3(CVT_G), blk, 0, stream>>>(w_k, wkb);
  cvt_kernel<<<dim3(CVT_G), blk, 0, stream>>>(w_v, wvb);
  cvt_kernel<<<dim3(CVT_G), blk, 0, stream>>>(w_g, wgb);
  cvt_kernel<<<dim3(CVT_G), blk, 0, stream>>>(w_o, wob);
  cvt_t2_kernel<<<dim3(160 * Cc / 256), blk, 0, stream>>>(maa_w1, w1t_hi, w1t_lo, 160);
  cvt_t2_kernel<<<dim3(64 * Cc / 256), blk, 0, stream>>>(dw1, dw1t_hi, dw1t_lo, 64);
  cvt_w2t_kernel<<<dim3(160 * Cc / 256), blk, 0, stream>>>(maa_w2, w2t_hi, w2t_lo);

  // 1. xm -> buf0
  prep_xm_kernel<<<dim3(BT * Cc / 256), blk, 0, stream>>>(hidden, maa_x, buf0);

  // 2. t5 = tanh(xm @ maa_w1): M=8192,N=160,K=2048 via split-K MFMA (hi/lo)
  mfma_skinny_kernel<10><<<dim3(128, SPLITK), blk, 0, stream>>>(
      buf0, w1t_hi, w1t_lo, pbuf, 2048 / SPLITK);
  reduce_tanh_kernel<<<dim3(BT * 160 / 256), blk, 0, stream>>>(pbuf, t5buf,
                                                               BT * 160);

  // 3. fused lerp (MFMA) -> xd(1) xk(2) xv(3) xr(4) xg(0)
  lerp5_mfma_kernel<<<dim3(64, 16), blk, 0, stream>>>(hidden, t5buf,
      w2t_hi, w2t_lo, maa_w, maa_k, maa_v, maa_r, maa_g,
      buf1, buf2, buf3, buf4, buf0);

  // 4. decay: a = tanh(xd @ dw1) [8192,64] via split-K MFMA (hi/lo);
  //    td = tdecay + a @ dw2 -> buf1 (VALU gemm, K=64)
  mfma_skinny_kernel<4><<<dim3(128, SPLITK), blk, 0, stream>>>(
      buf1, dw1t_hi, dw1t_lo, pbuf, 2048 / SPLITK);
  reduce_tanh_kernel<<<dim3(BT * 64 / 256), blk, 0, stream>>>(pbuf, abuf,
                                                              BT * 64);
  gemm_kernel<<<dim3(64, 16), blk, 0, stream>>>(abuf, dw2, buf1, tdecay,
                                                BT, Cc, 64, 0, 3);

  // 5. projections (MFMA): r->rscratch, k->buf4, v->buf2, g(silu)->buf3
  mfma_gemm_kernel<<<dim3(64, 16), blk, 0, stream>>>(buf4, wrb, rscratch, nullptr, 0);
  mfma_gemm_kernel<<<dim3(64, 16), blk, 0, stream>>>(buf2, wkb, buf4, nullptr, 0);
  mfma_gemm_kernel<<<dim3(64, 16), blk, 0, stream>>>(buf3, wvb, buf2, nullptr, 0);
  mfma_gemm_kernel<<<dim3(64, 16), blk, 0, stream>>>(buf0, wgb, buf3, nullptr, 2);

  // 6. chunked WKV scan: r=rscratch, k=buf4, v=buf2, td=buf1 -> out over buf1
  wkv_local_kernel<<<dim3(Bb * Hh * Gg), dim3(64), 0, stream>>>(
      buf4, buf2, buf1, slbuf, wpbuf);
  wkv_combine_kernel<<<dim3(Bb * Hh * Nn * Nn / 256), blk, 0, stream>>>(
      slbuf, wpbuf, ssbuf);
  wkv_out_kernel<<<dim3(Bb * Hh * Gg), dim3(64), 0, stream>>>(
      rscratch, buf4, buf2, buf1, faaaa, ssbuf, buf1);

  // 7. GroupNorm + gate -> buf4 (wkv out now lives in buf1)
  gn_gate_kernel<<<dim3(BT), blk, 0, stream>>>(buf1, buf3, lnw, lnb, buf4);

  // 8. final projection (MFMA) -> d_out fp32
  mfma_gemm_kernel<<<dim3(64, 16), blk, 0, stream>>>(buf4, wob, nullptr, outF, 4);
}